// Round 5
// baseline (648.093 us; speedup 1.0000x reference)
//
#include <hip/hip_runtime.h>
#include <math.h>

#define I_  2049
#define M_  2
#define J_  2048
#define K_  8
#define N_  2
#define NITER 5
#define EPSF 1e-20f
#define INVJ (1.0/2048.0)
#define CHUNK 16
#define NCHUNK 129  // ceil(2049/16)
#define SL 4        // j-slices for dw stage 1

// ---------- static device-global state ----------
__device__ float4 g_Xc[(size_t)I_*J_];      // 67 MB: Xc(I,J,M) — both m of a j in one float4
__device__ float2 g_T2[I_*K_];              // T[i][k][n=2]
__device__ float2 g_Told2[I_*K_];           // start-of-iter snapshot
__device__ float4 g_Vt4[(size_t)J_*4];      // V transposed: Vt[j][n][k] as 4x float4 per j
__device__ float2 g_W[I_*N_*M_];            // W[i][r][c]
__device__ float2 g_Wold[I_*N_*M_];         // iteration-start snapshot
__device__ float2 g_pnum[(size_t)NCHUNK*K_*J_];  // 17 MB partials (n in float2)
__device__ float2 g_pden[(size_t)NCHUNK*K_*J_];
__device__ double g_dpart[(size_t)I_*SL*12];     // dw stage-1 partials (787 KB)

__device__ __forceinline__ float frcp(float x) { return __builtin_amdgcn_rcpf(x); }

// ---------- double-complex helpers (per-i 2x2 solve only) ----------
struct dcx { double x, y; };
__device__ __forceinline__ dcx cmul(dcx a, dcx b) { return {a.x*b.x - a.y*b.y, a.x*b.y + a.y*b.x}; }
__device__ __forceinline__ dcx cadd(dcx a, dcx b) { return {a.x + b.x, a.y + b.y}; }
__device__ __forceinline__ dcx csub(dcx a, dcx b) { return {a.x - b.x, a.y - b.y}; }
__device__ __forceinline__ dcx cneg(dcx a) { return {-a.x, -a.y}; }
__device__ __forceinline__ dcx cdiv(dcx a, dcx b) {
  double d = b.x*b.x + b.y*b.y;
  return {(a.x*b.x + a.y*b.y)/d, (a.y*b.x - a.x*b.y)/d};
}
__device__ __forceinline__ dcx csqrt_(dcx z) {   // principal branch, numpy-compatible
  double r = hypot(z.x, z.y);
  if (r == 0.0) return {0.0, 0.0};
  double t = sqrt(0.5*(r + fabs(z.x)));
  if (z.x >= 0.0) return {t, z.y/(2.0*t)};
  return {fabs(z.y)/(2.0*t), (z.y >= 0.0) ? t : -t};
}

__device__ __forceinline__ float2 cyn(float2 w0, float2 w1, float2 x0, float2 x1) {
  float2 y;
  y.x = w0.x*x0.x - w0.y*x0.y + w1.x*x1.x - w1.y*x1.y;
  y.y = w0.x*x0.y + w0.y*x0.x + w1.x*x1.y + w1.y*x1.x;
  return y;
}

// ---------- per-i 2x2 solve (double), from g_dpart; writes g_W/g_Wold ----------
__device__ __forceinline__ void solve_i(int i, float2* wout) {
  double s_[12];
#pragma unroll
  for (int q = 0; q < 12; q++) {
    double v = 0.0;
#pragma unroll
    for (int w = 0; w < SL; w++) v += g_dpart[((size_t)i*SL + w)*12 + q];
    s_[q] = v;
  }
  dcx Wl[2][2];
  Wl[0][0] = {g_W[(size_t)i*4+0].x, g_W[(size_t)i*4+0].y};
  Wl[0][1] = {g_W[(size_t)i*4+1].x, g_W[(size_t)i*4+1].y};
  Wl[1][0] = {g_W[(size_t)i*4+2].x, g_W[(size_t)i*4+2].y};
  Wl[1][1] = {g_W[(size_t)i*4+3].x, g_W[(size_t)i*4+3].y};
#pragma unroll
  for (int n = 0; n < N_; n++) {
    dcx D00 = {s_[6*n+0]*INVJ, s_[6*n+1]*INVJ};
    dcx D01 = {s_[6*n+2]*INVJ, s_[6*n+3]*INVJ};
    dcx D11 = {s_[6*n+4]*INVJ, s_[6*n+5]*INVJ};
    dcx WD00 = cadd(cmul(Wl[0][0], D00), cmul(Wl[0][1], D01));
    dcx WD01 = cadd(cmul(Wl[0][0], D01), cmul(Wl[0][1], D11));
    dcx WD10 = cadd(cmul(Wl[1][0], D00), cmul(Wl[1][1], D01));
    dcx WD11 = cadd(cmul(Wl[1][0], D01), cmul(Wl[1][1], D11));
    dcx det = csub(cmul(WD00, WD11), cmul(WD01, WD10));
    dcx b0, b1;
    if (n == 0) { b0 = cdiv(WD11, det);        b1 = cdiv(cneg(WD10), det); }
    else        { b0 = cdiv(cneg(WD01), det);  b1 = cdiv(WD00, det); }
    dcx nrm = cadd(cmul(cmul(b0, b0), D00), cmul(cmul(b1, b1), D11));
    dcx tcr = cmul(cmul(b0, b1), D01); tcr.x *= 2.0; tcr.y *= 2.0;
    nrm = cadd(nrm, tcr);
    dcx sq = csqrt_(nrm);
    Wl[0][n] = cdiv(b0, sq);
    Wl[1][n] = cdiv(b1, sq);
  }
  float2 o00 = make_float2((float)Wl[0][0].x, (float)Wl[0][0].y);
  float2 o01 = make_float2((float)Wl[0][1].x, (float)Wl[0][1].y);
  float2 o10 = make_float2((float)Wl[1][0].x, (float)Wl[1][0].y);
  float2 o11 = make_float2((float)Wl[1][1].x, (float)Wl[1][1].y);
  g_W[(size_t)i*4+0] = o00; g_W[(size_t)i*4+1] = o01;
  g_W[(size_t)i*4+2] = o10; g_W[(size_t)i*4+3] = o11;
  g_Wold[(size_t)i*4+0] = o00; g_Wold[(size_t)i*4+1] = o01;
  g_Wold[(size_t)i*4+2] = o10; g_Wold[(size_t)i*4+3] = o11;
  wout[0] = o00; wout[1] = o01; wout[2] = o10; wout[3] = o11;
}

// ---------- setup: T<-T0, Vt<-V0 (transposed), W=Wold=eye ----------
__global__ __launch_bounds__(256) void k_setup(const float* __restrict__ T0,
                                               const float* __restrict__ V0) {
  int idx = blockIdx.x*256 + threadIdx.x;
  if (idx < I_*K_) g_T2[idx] = ((const float2*)T0)[idx];
  if (idx < K_*J_) {
    int k = idx >> 11, j = idx & (J_-1);
    float2 v = ((const float2*)V0)[idx];
    float* vtf = (float*)g_Vt4;
    vtf[j*16 + k]     = v.x;   // n=0
    vtf[j*16 + 8 + k] = v.y;   // n=1
  }
  if (idx < I_*N_*M_) {
    int r = (idx >> 1) & 1, c = idx & 1;
    float2 v = make_float2((r == c) ? 1.f : 0.f, 0.f);
    g_W[idx] = v;
    g_Wold[idx] = v;
  }
}

// ---------- transpose X(M,J,I,2) -> g_Xc(I,J,M); both m fused, float4 writes ----------
__global__ __launch_bounds__(256) void k_transpose(const float* __restrict__ X) {
  __shared__ float2 s0[32][65];   // [jj][ii], m=0
  __shared__ float2 s1[32][65];   // m=1
  int i0 = blockIdx.x*64, j0 = blockIdx.y*32;
  int lane = threadIdx.x & 63, row = threadIdx.x >> 6;
  const float2* X2 = (const float2*)X;   // (m*J + j)*I + i
  int gi = i0 + lane;
  if (gi < I_) {
    for (int jj = row; jj < 32; jj += 4) {
      s0[jj][lane] = X2[(size_t)(0*J_ + j0 + jj)*I_ + gi];
      s1[jj][lane] = X2[(size_t)(1*J_ + j0 + jj)*I_ + gi];
    }
  }
  __syncthreads();
  int jj = threadIdx.x & 31, ii0 = threadIdx.x >> 5;   // 32 lanes = 32 consecutive j (512B line)
  for (int u = 0; u < 8; u++) {
    int ii = ii0*8 + u;
    int i = i0 + ii;
    if (i < I_) {
      float2 a = s0[jj][ii], b = s1[jj][ii];
      g_Xc[(size_t)i*J_ + j0 + jj] = make_float4(a.x, a.y, b.x, b.y);
    }
  }
}

// ---------- T update: 1 i/block (2049 blocks), batched Xc, Vt loads, fast rcp,
// ---------- + in-block W solve (doSolve) replacing the separate dws2 kernel ----------
__global__ __launch_bounds__(256) void k_tupd4(int doSolve) {
  int i = blockIdx.x, t = threadIdx.x;
  __shared__ float2 sW[4];
  __shared__ float red[4][32];

  // issue the 8 Xc loads first (independent of W) — in flight during the solve
  float4 xv[8];
#pragma unroll
  for (int s = 0; s < 8; s++) xv[s] = g_Xc[(size_t)i*J_ + t + 256*s];
  float2 tk2[K_];
#pragma unroll
  for (int k = 0; k < K_; k++) tk2[k] = g_T2[(size_t)i*K_ + k];

  if (t == 0) {
    if (doSolve) {
      float2 w[4];
      solve_i(i, w);                     // W(t) = solve from prev iter's dws1 partials
      sW[0] = w[0]; sW[1] = w[1]; sW[2] = w[2]; sW[3] = w[3];
    } else {
      sW[0] = g_Wold[(size_t)i*4+0]; sW[1] = g_Wold[(size_t)i*4+1];
      sW[2] = g_Wold[(size_t)i*4+2]; sW[3] = g_Wold[(size_t)i*4+3];
    }
  }
  __syncthreads();
  float2 w00 = sW[0], w01 = sW[1], w10 = sW[2], w11 = sW[3];

  float aN0[K_], aD0[K_], aN1[K_], aD1[K_];
#pragma unroll
  for (int k = 0; k < K_; k++) { aN0[k]=0.f; aD0[k]=0.f; aN1[k]=0.f; aD1[k]=0.f; }
#pragma unroll
  for (int s = 0; s < 8; s++) {
    int j = t + 256*s;
    float4 vt0 = g_Vt4[(size_t)j*4+0], vt1 = g_Vt4[(size_t)j*4+1];   // n=0 k0-7
    float4 vt2 = g_Vt4[(size_t)j*4+2], vt3 = g_Vt4[(size_t)j*4+3];   // n=1 k0-7
    float vkx[K_] = {vt0.x,vt0.y,vt0.z,vt0.w,vt1.x,vt1.y,vt1.z,vt1.w};
    float vky[K_] = {vt2.x,vt2.y,vt2.z,vt2.w,vt3.x,vt3.y,vt3.z,vt3.w};
    float rn0 = 0.f, rn1 = 0.f;
#pragma unroll
    for (int k = 0; k < K_; k++) {
      rn0 = fmaf(tk2[k].x, vkx[k], rn0);
      rn1 = fmaf(tk2[k].y, vky[k], rn1);
    }
    float2 x0 = make_float2(xv[s].x, xv[s].y);
    float2 x1 = make_float2(xv[s].z, xv[s].w);
    float2 y0 = cyn(w00, w01, x0, x1);
    float2 y1 = cyn(w10, w11, x0, x1);
    float p0  = (y0.x*y0.x + y0.y*y0.y) * frcp(rn0*rn0 + EPSF);
    float p1  = (y1.x*y1.x + y1.y*y1.y) * frcp(rn1*rn1 + EPSF);
    float rd0 = frcp(rn0), rd1 = frcp(rn1);
#pragma unroll
    for (int k = 0; k < K_; k++) {
      aN0[k] = fmaf(p0,  vkx[k], aN0[k]);
      aD0[k] = fmaf(rd0, vkx[k], aD0[k]);
      aN1[k] = fmaf(p1,  vky[k], aN1[k]);
      aD1[k] = fmaf(rd1, vky[k], aD1[k]);
    }
  }
#pragma unroll
  for (int k = 0; k < K_; k++)
    for (int off = 32; off; off >>= 1) {
      aN0[k] += __shfl_down(aN0[k], off);
      aD0[k] += __shfl_down(aD0[k], off);
      aN1[k] += __shfl_down(aN1[k], off);
      aD1[k] += __shfl_down(aD1[k], off);
    }
  int wave = t >> 6, lane = t & 63;
  if (lane == 0) {
#pragma unroll
    for (int k = 0; k < K_; k++) {
      red[wave][k]      = aN0[k];
      red[wave][8 + k]  = aD0[k];
      red[wave][16 + k] = aN1[k];
      red[wave][24 + k] = aD1[k];
    }
  }
  __syncthreads();
  if (t < 8) {
    int k = t;
    float n0 = red[0][k]    + red[1][k]    + red[2][k]    + red[3][k];
    float d0 = red[0][8+k]  + red[1][8+k]  + red[2][8+k]  + red[3][8+k];
    float n1 = red[0][16+k] + red[1][16+k] + red[2][16+k] + red[3][16+k];
    float d1 = red[0][24+k] + red[1][24+k] + red[2][24+k] + red[3][24+k];
    float2 tv = tk2[k];
    g_Told2[(size_t)i*K_ + k] = tv;
    g_T2[(size_t)i*K_ + k] = make_float2(tv.x * sqrtf(n0/d0), tv.y * sqrtf(n1/d1));
  }
}

// ---------- V partial accumulation, both n; per-chunk partial write (CHUNK=16) ----------
__global__ __launch_bounds__(256) void k_vupd2() {
  int t  = threadIdx.x;
  int j  = blockIdx.x*256 + t;
  int c  = blockIdx.y;
  int i0 = c*CHUNK;
  int ni = I_ - i0; if (ni > CHUNK) ni = CHUNK;

  __shared__ float2 sWold[CHUNK*4];
  __shared__ float2 sTold[CHUNK*8];
  __shared__ float2 sT[CHUNK*8];
  for (int u = t; u < CHUNK*20; u += 256) {
    if (u < CHUNK*4) {
      int g = i0*4 + u;              if (g < I_*4) sWold[u] = g_Wold[g];
    } else if (u < CHUNK*12) {
      int g = i0*8 + (u - CHUNK*4);  if (g < I_*8) sTold[u - CHUNK*4] = g_Told2[g];
    } else {
      int g = i0*8 + (u - CHUNK*12); if (g < I_*8) sT[u - CHUNK*12] = g_T2[g];
    }
  }
  __syncthreads();

  float4 vt0 = g_Vt4[(size_t)j*4+0], vt1 = g_Vt4[(size_t)j*4+1];
  float4 vt2 = g_Vt4[(size_t)j*4+2], vt3 = g_Vt4[(size_t)j*4+3];
  float vkx[K_] = {vt0.x,vt0.y,vt0.z,vt0.w,vt1.x,vt1.y,vt1.z,vt1.w};
  float vky[K_] = {vt2.x,vt2.y,vt2.z,vt2.w,vt3.x,vt3.y,vt3.z,vt3.w};
  float aN0[K_], aD0[K_], aN1[K_], aD1[K_];
#pragma unroll
  for (int k = 0; k < K_; k++) { aN0[k]=0.f; aD0[k]=0.f; aN1[k]=0.f; aD1[k]=0.f; }

  auto body = [&](int ii, float4 xv) {
    float2 x0 = make_float2(xv.x, xv.y);
    float2 x1 = make_float2(xv.z, xv.w);
    float2 w00 = sWold[ii*4 + 0], w01 = sWold[ii*4 + 1];
    float2 w10 = sWold[ii*4 + 2], w11 = sWold[ii*4 + 3];
    float rn0 = 0.f, rn1 = 0.f;
#pragma unroll
    for (int k = 0; k < K_; k++) {
      float2 to = sTold[ii*8 + k];
      rn0 = fmaf(to.x, vkx[k], rn0);
      rn1 = fmaf(to.y, vky[k], rn1);
    }
    float2 y0 = cyn(w00, w01, x0, x1);
    float2 y1 = cyn(w10, w11, x0, x1);
    float p0  = (y0.x*y0.x + y0.y*y0.y) * frcp(rn0*rn0 + EPSF);
    float p1  = (y1.x*y1.x + y1.y*y1.y) * frcp(rn1*rn1 + EPSF);
    float rd0 = frcp(rn0), rd1 = frcp(rn1);
#pragma unroll
    for (int k = 0; k < K_; k++) {
      float2 tn = sT[ii*8 + k];
      aN0[k] = fmaf(tn.x, p0,  aN0[k]);
      aD0[k] = fmaf(tn.x, rd0, aD0[k]);
      aN1[k] = fmaf(tn.y, p1,  aN1[k]);
      aD1[k] = fmaf(tn.y, rd1, aD1[k]);
    }
  };

  int ii = 0;
  for (; ii + 8 <= ni; ii += 8) {
    float4 xv[8];
#pragma unroll
    for (int u = 0; u < 8; u++) xv[u] = g_Xc[(size_t)(i0 + ii + u)*J_ + j];
#pragma unroll
    for (int u = 0; u < 8; u++) body(ii + u, xv[u]);
  }
  for (; ii < ni; ii++) {
    float4 xv = g_Xc[(size_t)(i0 + ii)*J_ + j];
    body(ii, xv);
  }

  size_t base = (size_t)c*(K_*J_);
#pragma unroll
  for (int k = 0; k < K_; k++) {
    g_pnum[base + (size_t)k*J_ + j] = make_float2(aN0[k], aN1[k]);
    g_pden[base + (size_t)k*J_ + j] = make_float2(aD0[k], aD1[k]);
  }
}

// ---------- chunk-reduce partials + apply Vt *= sqrt(num/den); 1024 blocks ----------
__global__ __launch_bounds__(256) void k_vapply2() {
  int t = threadIdx.x;
  int idx = blockIdx.x*16 + (t & 15);       // kj index, 1024 blocks x 16
  int slice = t >> 4;                       // 16 c-slices of 9 (16*9=144 >= 129)
  int c0 = slice*9, c1 = c0 + 9; if (c1 > NCHUNK) c1 = NCHUNK;
  float2 sn = make_float2(0.f, 0.f), sd = make_float2(0.f, 0.f);
  for (int c = c0; c < c1; c++) {
    float2 a = g_pnum[(size_t)c*(K_*J_) + idx];
    float2 b = g_pden[(size_t)c*(K_*J_) + idx];
    sn.x += a.x; sn.y += a.y; sd.x += b.x; sd.y += b.y;
  }
  __shared__ float2 rN[16][16], rD[16][16];
  rN[slice][t & 15] = sn; rD[slice][t & 15] = sd;
  __syncthreads();
  if (t < 16) {
    float2 n = rN[0][t], d = rD[0][t];
#pragma unroll
    for (int s = 1; s < 16; s++) {
      n.x += rN[s][t].x; n.y += rN[s][t].y;
      d.x += rD[s][t].x; d.y += rD[s][t].y;
    }
    int kk = idx >> 11, j = idx & (J_-1);
    float* vtf = (float*)g_Vt4;
    float v0 = vtf[j*16 + kk], v1 = vtf[j*16 + 8 + kk];
    vtf[j*16 + kk]     = v0 * sqrtf(n.x/d.x);
    vtf[j*16 + 8 + kk] = v1 * sqrtf(n.y/d.y);
  }
}

// ---------- dw stage 1: D partial accumulation; 4 independent slice-waves per i ----------
__global__ __launch_bounds__(256) void k_dws1() {
  int i = blockIdx.x, t = threadIdx.x;
  int wv = t >> 6, lane = t & 63;         // wv = j-slice 0..3
  float2 tk2[K_];
#pragma unroll
  for (int k = 0; k < K_; k++) tk2[k] = g_T2[(size_t)i*K_ + k];
  // batch the 8 Xc loads for this wave's 512-j slice
  float4 xv[8];
#pragma unroll
  for (int s = 0; s < 8; s++) xv[s] = g_Xc[(size_t)i*J_ + wv*512 + s*64 + lane];
  double acc[12];
#pragma unroll
  for (int q = 0; q < 12; q++) acc[q] = 0.0;
#pragma unroll
  for (int s = 0; s < 8; s++) {
    int j = wv*512 + s*64 + lane;
    float4 vt0 = g_Vt4[(size_t)j*4+0], vt1 = g_Vt4[(size_t)j*4+1];
    float4 vt2 = g_Vt4[(size_t)j*4+2], vt3 = g_Vt4[(size_t)j*4+3];
    float vkx[K_] = {vt0.x,vt0.y,vt0.z,vt0.w,vt1.x,vt1.y,vt1.z,vt1.w};
    float vky[K_] = {vt2.x,vt2.y,vt2.z,vt2.w,vt3.x,vt3.y,vt3.z,vt3.w};
    float rn0 = 0.f, rn1 = 0.f;
#pragma unroll
    for (int k = 0; k < K_; k++) {
      rn0 = fmaf(tk2[k].x, vkx[k], rn0);
      rn1 = fmaf(tk2[k].y, vky[k], rn1);
    }
    double a0 = xv[s].x, b0 = xv[s].y, a1 = xv[s].z, b1 = xv[s].w;
    double d00r = a0*a0 - b0*b0, d00i = 2.0*a0*b0;
    double d01r = a0*a1 - b0*b1, d01i = a0*b1 + a1*b0;
    double d11r = a1*a1 - b1*b1, d11i = 2.0*a1*b1;
    double inv0 = (double)frcp(rn0), inv1 = (double)frcp(rn1);
    acc[0] += d00r*inv0; acc[1] += d00i*inv0;
    acc[2] += d01r*inv0; acc[3] += d01i*inv0;
    acc[4] += d11r*inv0; acc[5] += d11i*inv0;
    acc[6]  += d00r*inv1; acc[7]  += d00i*inv1;
    acc[8]  += d01r*inv1; acc[9]  += d01i*inv1;
    acc[10] += d11r*inv1; acc[11] += d11i*inv1;
  }
#pragma unroll
  for (int q = 0; q < 12; q++)
    for (int off = 32; off; off >>= 1) acc[q] += __shfl_down(acc[q], off);
  if (lane == 0) {
#pragma unroll
    for (int q = 0; q < 12; q++) g_dpart[((size_t)i*SL + wv)*12 + q] = acc[q];
  }
}

// ---------- final: in-block solve of last iter's W + Y = W · Xc output ----------
__global__ __launch_bounds__(256) void k_yout(float* __restrict__ out, int cplx) {
  int i = blockIdx.x, t = threadIdx.x;
  __shared__ float2 sW[4];
  float4 xv[8];
#pragma unroll
  for (int s = 0; s < 8; s++) xv[s] = g_Xc[(size_t)i*J_ + t + 256*s];
  if (t == 0) {
    float2 w[4];
    solve_i(i, w);
    sW[0] = w[0]; sW[1] = w[1]; sW[2] = w[2]; sW[3] = w[3];
  }
  __syncthreads();
  float2 w00 = sW[0], w01 = sW[1], w10 = sW[2], w11 = sW[3];
  float2* out2 = (float2*)out;
#pragma unroll
  for (int s = 0; s < 8; s++) {
    int j = t + 256*s;
    float2 x0 = make_float2(xv[s].x, xv[s].y);
    float2 x1 = make_float2(xv[s].z, xv[s].w);
    float2 y0 = cyn(w00, w01, x0, x1);
    float2 y1 = cyn(w10, w11, x0, x1);
    if (cplx) {
      out2[((size_t)i*N_ + 0)*J_ + j] = y0;
      out2[((size_t)i*N_ + 1)*J_ + j] = y1;
    } else {      // float32(complex) == real part
      out[((size_t)i*N_ + 0)*J_ + j] = y0.x;
      out[((size_t)i*N_ + 1)*J_ + j] = y1.x;
    }
  }
}

extern "C" void kernel_launch(void* const* d_in, const int* in_sizes, int n_in,
                              void* d_out, int out_size, void* d_ws, size_t ws_size,
                              hipStream_t stream) {
  const float* X  = (const float*)d_in[0];
  const float* T0 = (const float*)d_in[1];
  const float* V0 = (const float*)d_in[2];
  (void)d_ws; (void)ws_size;

  k_setup<<<(I_*K_ + 255)/256, 256, 0, stream>>>(T0, V0);
  k_transpose<<<dim3((I_ + 63)/64, J_/32), 256, 0, stream>>>(X);

  int cplx = (out_size >= 2*I_*N_*J_) ? 1 : 0;
  for (int it = 0; it < NITER; it++) {
    // W-solve for iter 'it' happens inside k_tupd4 (from prev iter's dws1 partials)
    k_tupd4<<<I_, 256, 0, stream>>>(it > 0);
    k_vupd2<<<dim3(J_/256, NCHUNK), 256, 0, stream>>>();
    k_vapply2<<<K_*J_/16, 256, 0, stream>>>();
    k_dws1<<<I_, 256, 0, stream>>>();
  }
  k_yout<<<I_, 256, 0, stream>>>((float*)d_out, cplx);   // includes final W solve
}

// Round 6
// 611.563 us; speedup vs baseline: 1.0597x; 1.0597x over previous
//
#include <hip/hip_runtime.h>
#include <math.h>

#define I_  2049
#define M_  2
#define J_  2048
#define K_  8
#define N_  2
#define NITER 5
#define EPSF 1e-20f
#define INVJ (1.0/2048.0)
#define CHUNK 16
#define NCHUNK 129  // ceil(2049/16)

// ---------- static device-global state ----------
__device__ float4 g_Xc[(size_t)I_*J_];      // 67 MB: Xc(I,J,M) — both m of a j in one float4
__device__ float2 g_T2[I_*K_];              // T[i][k][n=2]
__device__ float2 g_Told2[I_*K_];           // start-of-iter snapshot
__device__ float4 g_Vt4[(size_t)J_*4];      // V transposed: Vt[j][n][k] as 4x float4 per j
__device__ float2 g_W[I_*N_*M_];            // W[i][r][c]
__device__ float2 g_Wold[I_*N_*M_];         // iteration-start snapshot
__device__ float2 g_pnum[(size_t)NCHUNK*K_*J_];  // 17 MB partials (n in float2)
__device__ float2 g_pden[(size_t)NCHUNK*K_*J_];

__device__ __forceinline__ float frcp(float x) { return __builtin_amdgcn_rcpf(x); }

// ---------- double-complex helpers (per-i 2x2 solve only) ----------
struct dcx { double x, y; };
__device__ __forceinline__ dcx cmul(dcx a, dcx b) { return {a.x*b.x - a.y*b.y, a.x*b.y + a.y*b.x}; }
__device__ __forceinline__ dcx cadd(dcx a, dcx b) { return {a.x + b.x, a.y + b.y}; }
__device__ __forceinline__ dcx csub(dcx a, dcx b) { return {a.x - b.x, a.y - b.y}; }
__device__ __forceinline__ dcx cneg(dcx a) { return {-a.x, -a.y}; }
__device__ __forceinline__ dcx cdiv(dcx a, dcx b) {
  double d = b.x*b.x + b.y*b.y;
  return {(a.x*b.x + a.y*b.y)/d, (a.y*b.x - a.x*b.y)/d};
}
__device__ __forceinline__ dcx csqrt_(dcx z) {   // principal branch, numpy-compatible
  double r = hypot(z.x, z.y);
  if (r == 0.0) return {0.0, 0.0};
  double t = sqrt(0.5*(r + fabs(z.x)));
  if (z.x >= 0.0) return {t, z.y/(2.0*t)};
  return {fabs(z.y)/(2.0*t), (z.y >= 0.0) ? t : -t};
}

__device__ __forceinline__ float2 cyn(float2 w0, float2 w1, float2 x0, float2 x1) {
  float2 y;
  y.x = w0.x*x0.x - w0.y*x0.y + w1.x*x1.x - w1.y*x1.y;
  y.y = w0.x*x0.y + w0.y*x0.x + w1.x*x1.y + w1.y*x1.x;
  return y;
}

// ---------- per-i 2x2 solve (double) from 12 summed moments; writes g_W/g_Wold ----------
__device__ __forceinline__ void solve12(int i, const double* s_, float2* wout) {
  dcx Wl[2][2];
  Wl[0][0] = {g_W[(size_t)i*4+0].x, g_W[(size_t)i*4+0].y};
  Wl[0][1] = {g_W[(size_t)i*4+1].x, g_W[(size_t)i*4+1].y};
  Wl[1][0] = {g_W[(size_t)i*4+2].x, g_W[(size_t)i*4+2].y};
  Wl[1][1] = {g_W[(size_t)i*4+3].x, g_W[(size_t)i*4+3].y};
#pragma unroll
  for (int n = 0; n < N_; n++) {
    dcx D00 = {s_[6*n+0]*INVJ, s_[6*n+1]*INVJ};
    dcx D01 = {s_[6*n+2]*INVJ, s_[6*n+3]*INVJ};
    dcx D11 = {s_[6*n+4]*INVJ, s_[6*n+5]*INVJ};
    dcx WD00 = cadd(cmul(Wl[0][0], D00), cmul(Wl[0][1], D01));
    dcx WD01 = cadd(cmul(Wl[0][0], D01), cmul(Wl[0][1], D11));
    dcx WD10 = cadd(cmul(Wl[1][0], D00), cmul(Wl[1][1], D01));
    dcx WD11 = cadd(cmul(Wl[1][0], D01), cmul(Wl[1][1], D11));
    dcx det = csub(cmul(WD00, WD11), cmul(WD01, WD10));
    dcx b0, b1;
    if (n == 0) { b0 = cdiv(WD11, det);        b1 = cdiv(cneg(WD10), det); }
    else        { b0 = cdiv(cneg(WD01), det);  b1 = cdiv(WD00, det); }
    dcx nrm = cadd(cmul(cmul(b0, b0), D00), cmul(cmul(b1, b1), D11));
    dcx tcr = cmul(cmul(b0, b1), D01); tcr.x *= 2.0; tcr.y *= 2.0;
    nrm = cadd(nrm, tcr);
    dcx sq = csqrt_(nrm);
    Wl[0][n] = cdiv(b0, sq);
    Wl[1][n] = cdiv(b1, sq);
  }
  float2 o00 = make_float2((float)Wl[0][0].x, (float)Wl[0][0].y);
  float2 o01 = make_float2((float)Wl[0][1].x, (float)Wl[0][1].y);
  float2 o10 = make_float2((float)Wl[1][0].x, (float)Wl[1][0].y);
  float2 o11 = make_float2((float)Wl[1][1].x, (float)Wl[1][1].y);
  g_W[(size_t)i*4+0] = o00; g_W[(size_t)i*4+1] = o01;
  g_W[(size_t)i*4+2] = o10; g_W[(size_t)i*4+3] = o11;
  g_Wold[(size_t)i*4+0] = o00; g_Wold[(size_t)i*4+1] = o01;
  g_Wold[(size_t)i*4+2] = o10; g_Wold[(size_t)i*4+3] = o11;
  wout[0] = o00; wout[1] = o01; wout[2] = o10; wout[3] = o11;
}

// ---------- setup: T<-T0, Vt<-V0 (transposed), W=Wold=eye ----------
__global__ __launch_bounds__(256) void k_setup(const float* __restrict__ T0,
                                               const float* __restrict__ V0) {
  int idx = blockIdx.x*256 + threadIdx.x;
  if (idx < I_*K_) g_T2[idx] = ((const float2*)T0)[idx];
  if (idx < K_*J_) {
    int k = idx >> 11, j = idx & (J_-1);
    float2 v = ((const float2*)V0)[idx];
    float* vtf = (float*)g_Vt4;
    vtf[j*16 + k]     = v.x;   // n=0
    vtf[j*16 + 8 + k] = v.y;   // n=1
  }
  if (idx < I_*N_*M_) {
    int r = (idx >> 1) & 1, c = idx & 1;
    float2 v = make_float2((r == c) ? 1.f : 0.f, 0.f);
    g_W[idx] = v;
    g_Wold[idx] = v;
  }
}

// ---------- transpose X(M,J,I,2) -> g_Xc(I,J,M); both m fused, float4 writes ----------
__global__ __launch_bounds__(256) void k_transpose(const float* __restrict__ X) {
  __shared__ float2 s0[32][65];   // [jj][ii], m=0
  __shared__ float2 s1[32][65];   // m=1
  int i0 = blockIdx.x*64, j0 = blockIdx.y*32;
  int lane = threadIdx.x & 63, row = threadIdx.x >> 6;
  const float2* X2 = (const float2*)X;   // (m*J + j)*I + i
  int gi = i0 + lane;
  if (gi < I_) {
    for (int jj = row; jj < 32; jj += 4) {
      s0[jj][lane] = X2[(size_t)(0*J_ + j0 + jj)*I_ + gi];
      s1[jj][lane] = X2[(size_t)(1*J_ + j0 + jj)*I_ + gi];
    }
  }
  __syncthreads();
  int jj = threadIdx.x & 31, ii0 = threadIdx.x >> 5;   // 32 lanes = 32 consecutive j (512B line)
  for (int u = 0; u < 8; u++) {
    int ii = ii0*8 + u;
    int i = i0 + ii;
    if (i < I_) {
      float2 a = s0[jj][ii], b = s1[jj][ii];
      g_Xc[(size_t)i*J_ + j0 + jj] = make_float4(a.x, a.y, b.x, b.y);
    }
  }
}

// ---------- fused per-i kernel: [D-accum + mid-block solve] (doD) + T-update ----------
// doD=1: phase 1 computes D(i) over all j (4 wave-slices, f32 accum like the f32 reference),
// block-reduce, thread-0 double solve -> W; phase 2 T-update re-reads the row L2/L3-hot.
// doD=0 (iteration 0): W = Wold (identity). No registers held across barriers.
__global__ __launch_bounds__(256) void k_tv(int doD) {
  int i = blockIdx.x, t = threadIdx.x;
  int wv = t >> 6, lane = t & 63;
  __shared__ float redD[4][12];
  __shared__ float2 sW[4];
  __shared__ float redT[4][32];

  float2 tk2[K_];
#pragma unroll
  for (int k = 0; k < K_; k++) tk2[k] = g_T2[(size_t)i*K_ + k];

  if (doD) {
    // ---- phase 1: D moments over this wave's 512-j slice ----
    float4 xv[8];
#pragma unroll
    for (int s = 0; s < 8; s++) xv[s] = g_Xc[(size_t)i*J_ + wv*512 + s*64 + lane];
    float acc[12];
#pragma unroll
    for (int q = 0; q < 12; q++) acc[q] = 0.f;
#pragma unroll
    for (int s = 0; s < 8; s++) {
      int j = wv*512 + s*64 + lane;
      float4 vt0 = g_Vt4[(size_t)j*4+0], vt1 = g_Vt4[(size_t)j*4+1];
      float4 vt2 = g_Vt4[(size_t)j*4+2], vt3 = g_Vt4[(size_t)j*4+3];
      float vkx[K_] = {vt0.x,vt0.y,vt0.z,vt0.w,vt1.x,vt1.y,vt1.z,vt1.w};
      float vky[K_] = {vt2.x,vt2.y,vt2.z,vt2.w,vt3.x,vt3.y,vt3.z,vt3.w};
      float rn0 = 0.f, rn1 = 0.f;
#pragma unroll
      for (int k = 0; k < K_; k++) {
        rn0 = fmaf(tk2[k].x, vkx[k], rn0);
        rn1 = fmaf(tk2[k].y, vky[k], rn1);
      }
      float a0 = xv[s].x, b0 = xv[s].y, a1 = xv[s].z, b1 = xv[s].w;
      float d00r = a0*a0 - b0*b0, d00i = 2.f*a0*b0;
      float d01r = a0*a1 - b0*b1, d01i = a0*b1 + a1*b0;
      float d11r = a1*a1 - b1*b1, d11i = 2.f*a1*b1;
      float inv0 = frcp(rn0), inv1 = frcp(rn1);
      acc[0] = fmaf(d00r, inv0, acc[0]); acc[1] = fmaf(d00i, inv0, acc[1]);
      acc[2] = fmaf(d01r, inv0, acc[2]); acc[3] = fmaf(d01i, inv0, acc[3]);
      acc[4] = fmaf(d11r, inv0, acc[4]); acc[5] = fmaf(d11i, inv0, acc[5]);
      acc[6] = fmaf(d00r, inv1, acc[6]); acc[7] = fmaf(d00i, inv1, acc[7]);
      acc[8] = fmaf(d01r, inv1, acc[8]); acc[9] = fmaf(d01i, inv1, acc[9]);
      acc[10]= fmaf(d11r, inv1, acc[10]);acc[11]= fmaf(d11i, inv1, acc[11]);
    }
#pragma unroll
    for (int q = 0; q < 12; q++)
      for (int off = 32; off; off >>= 1) acc[q] += __shfl_down(acc[q], off);
    if (lane == 0) {
#pragma unroll
      for (int q = 0; q < 12; q++) redD[wv][q] = acc[q];
    }
    __syncthreads();
    if (t == 0) {
      double s_[12];
#pragma unroll
      for (int q = 0; q < 12; q++)
        s_[q] = (double)redD[0][q] + (double)redD[1][q] + (double)redD[2][q] + (double)redD[3][q];
      float2 w[4];
      solve12(i, s_, w);
      sW[0] = w[0]; sW[1] = w[1]; sW[2] = w[2]; sW[3] = w[3];
    }
  } else {
    if (t == 0) {
      sW[0] = g_Wold[(size_t)i*4+0]; sW[1] = g_Wold[(size_t)i*4+1];
      sW[2] = g_Wold[(size_t)i*4+2]; sW[3] = g_Wold[(size_t)i*4+3];
    }
  }
  __syncthreads();
  float2 w00 = sW[0], w01 = sW[1], w10 = sW[2], w11 = sW[3];

  // ---- phase 2: T update (row is L2/L3-hot when doD) ----
  float4 xv2[8];
#pragma unroll
  for (int s = 0; s < 8; s++) xv2[s] = g_Xc[(size_t)i*J_ + t + 256*s];
  float aN0[K_], aD0[K_], aN1[K_], aD1[K_];
#pragma unroll
  for (int k = 0; k < K_; k++) { aN0[k]=0.f; aD0[k]=0.f; aN1[k]=0.f; aD1[k]=0.f; }
#pragma unroll
  for (int s = 0; s < 8; s++) {
    int j = t + 256*s;
    float4 vt0 = g_Vt4[(size_t)j*4+0], vt1 = g_Vt4[(size_t)j*4+1];
    float4 vt2 = g_Vt4[(size_t)j*4+2], vt3 = g_Vt4[(size_t)j*4+3];
    float vkx[K_] = {vt0.x,vt0.y,vt0.z,vt0.w,vt1.x,vt1.y,vt1.z,vt1.w};
    float vky[K_] = {vt2.x,vt2.y,vt2.z,vt2.w,vt3.x,vt3.y,vt3.z,vt3.w};
    float rn0 = 0.f, rn1 = 0.f;
#pragma unroll
    for (int k = 0; k < K_; k++) {
      rn0 = fmaf(tk2[k].x, vkx[k], rn0);
      rn1 = fmaf(tk2[k].y, vky[k], rn1);
    }
    float2 x0 = make_float2(xv2[s].x, xv2[s].y);
    float2 x1 = make_float2(xv2[s].z, xv2[s].w);
    float2 y0 = cyn(w00, w01, x0, x1);
    float2 y1 = cyn(w10, w11, x0, x1);
    float p0  = (y0.x*y0.x + y0.y*y0.y) * frcp(rn0*rn0 + EPSF);
    float p1  = (y1.x*y1.x + y1.y*y1.y) * frcp(rn1*rn1 + EPSF);
    float rd0 = frcp(rn0), rd1 = frcp(rn1);
#pragma unroll
    for (int k = 0; k < K_; k++) {
      aN0[k] = fmaf(p0,  vkx[k], aN0[k]);
      aD0[k] = fmaf(rd0, vkx[k], aD0[k]);
      aN1[k] = fmaf(p1,  vky[k], aN1[k]);
      aD1[k] = fmaf(rd1, vky[k], aD1[k]);
    }
  }
#pragma unroll
  for (int k = 0; k < K_; k++)
    for (int off = 32; off; off >>= 1) {
      aN0[k] += __shfl_down(aN0[k], off);
      aD0[k] += __shfl_down(aD0[k], off);
      aN1[k] += __shfl_down(aN1[k], off);
      aD1[k] += __shfl_down(aD1[k], off);
    }
  if (lane == 0) {
#pragma unroll
    for (int k = 0; k < K_; k++) {
      redT[wv][k]      = aN0[k];
      redT[wv][8 + k]  = aD0[k];
      redT[wv][16 + k] = aN1[k];
      redT[wv][24 + k] = aD1[k];
    }
  }
  __syncthreads();
  if (t < 8) {
    int k = t;
    float n0 = redT[0][k]    + redT[1][k]    + redT[2][k]    + redT[3][k];
    float d0 = redT[0][8+k]  + redT[1][8+k]  + redT[2][8+k]  + redT[3][8+k];
    float n1 = redT[0][16+k] + redT[1][16+k] + redT[2][16+k] + redT[3][16+k];
    float d1 = redT[0][24+k] + redT[1][24+k] + redT[2][24+k] + redT[3][24+k];
    float2 tv = tk2[k];
    g_Told2[(size_t)i*K_ + k] = tv;
    g_T2[(size_t)i*K_ + k] = make_float2(tv.x * sqrtf(n0/d0), tv.y * sqrtf(n1/d1));
  }
}

// ---------- V partial accumulation, both n; per-chunk partial write (CHUNK=16) ----------
__global__ __launch_bounds__(256) void k_vupd2() {
  int t  = threadIdx.x;
  int j  = blockIdx.x*256 + t;
  int c  = blockIdx.y;
  int i0 = c*CHUNK;
  int ni = I_ - i0; if (ni > CHUNK) ni = CHUNK;

  __shared__ float2 sWold[CHUNK*4];
  __shared__ float2 sTold[CHUNK*8];
  __shared__ float2 sT[CHUNK*8];
  for (int u = t; u < CHUNK*20; u += 256) {
    if (u < CHUNK*4) {
      int g = i0*4 + u;              if (g < I_*4) sWold[u] = g_Wold[g];
    } else if (u < CHUNK*12) {
      int g = i0*8 + (u - CHUNK*4);  if (g < I_*8) sTold[u - CHUNK*4] = g_Told2[g];
    } else {
      int g = i0*8 + (u - CHUNK*12); if (g < I_*8) sT[u - CHUNK*12] = g_T2[g];
    }
  }
  __syncthreads();

  float4 vt0 = g_Vt4[(size_t)j*4+0], vt1 = g_Vt4[(size_t)j*4+1];
  float4 vt2 = g_Vt4[(size_t)j*4+2], vt3 = g_Vt4[(size_t)j*4+3];
  float vkx[K_] = {vt0.x,vt0.y,vt0.z,vt0.w,vt1.x,vt1.y,vt1.z,vt1.w};
  float vky[K_] = {vt2.x,vt2.y,vt2.z,vt2.w,vt3.x,vt3.y,vt3.z,vt3.w};
  float aN0[K_], aD0[K_], aN1[K_], aD1[K_];
#pragma unroll
  for (int k = 0; k < K_; k++) { aN0[k]=0.f; aD0[k]=0.f; aN1[k]=0.f; aD1[k]=0.f; }

  auto body = [&](int ii, float4 xv) {
    float2 x0 = make_float2(xv.x, xv.y);
    float2 x1 = make_float2(xv.z, xv.w);
    float2 w00 = sWold[ii*4 + 0], w01 = sWold[ii*4 + 1];
    float2 w10 = sWold[ii*4 + 2], w11 = sWold[ii*4 + 3];
    float rn0 = 0.f, rn1 = 0.f;
#pragma unroll
    for (int k = 0; k < K_; k++) {
      float2 to = sTold[ii*8 + k];
      rn0 = fmaf(to.x, vkx[k], rn0);
      rn1 = fmaf(to.y, vky[k], rn1);
    }
    float2 y0 = cyn(w00, w01, x0, x1);
    float2 y1 = cyn(w10, w11, x0, x1);
    float p0  = (y0.x*y0.x + y0.y*y0.y) * frcp(rn0*rn0 + EPSF);
    float p1  = (y1.x*y1.x + y1.y*y1.y) * frcp(rn1*rn1 + EPSF);
    float rd0 = frcp(rn0), rd1 = frcp(rn1);
#pragma unroll
    for (int k = 0; k < K_; k++) {
      float2 tn = sT[ii*8 + k];
      aN0[k] = fmaf(tn.x, p0,  aN0[k]);
      aD0[k] = fmaf(tn.x, rd0, aD0[k]);
      aN1[k] = fmaf(tn.y, p1,  aN1[k]);
      aD1[k] = fmaf(tn.y, rd1, aD1[k]);
    }
  };

  int ii = 0;
  for (; ii + 8 <= ni; ii += 8) {
    float4 xv[8];
#pragma unroll
    for (int u = 0; u < 8; u++) xv[u] = g_Xc[(size_t)(i0 + ii + u)*J_ + j];
#pragma unroll
    for (int u = 0; u < 8; u++) body(ii + u, xv[u]);
  }
  for (; ii < ni; ii++) {
    float4 xv = g_Xc[(size_t)(i0 + ii)*J_ + j];
    body(ii, xv);
  }

  size_t base = (size_t)c*(K_*J_);
#pragma unroll
  for (int k = 0; k < K_; k++) {
    g_pnum[base + (size_t)k*J_ + j] = make_float2(aN0[k], aN1[k]);
    g_pden[base + (size_t)k*J_ + j] = make_float2(aD0[k], aD1[k]);
  }
}

// ---------- chunk-reduce partials + apply Vt *= sqrt(num/den); 1024 blocks ----------
__global__ __launch_bounds__(256) void k_vapply2() {
  int t = threadIdx.x;
  int idx = blockIdx.x*16 + (t & 15);       // kj index, 1024 blocks x 16
  int slice = t >> 4;                       // 16 c-slices of 9 (16*9=144 >= 129)
  int c0 = slice*9, c1 = c0 + 9; if (c1 > NCHUNK) c1 = NCHUNK;
  float2 sn = make_float2(0.f, 0.f), sd = make_float2(0.f, 0.f);
  for (int c = c0; c < c1; c++) {
    float2 a = g_pnum[(size_t)c*(K_*J_) + idx];
    float2 b = g_pden[(size_t)c*(K_*J_) + idx];
    sn.x += a.x; sn.y += a.y; sd.x += b.x; sd.y += b.y;
  }
  __shared__ float2 rN[16][16], rD[16][16];
  rN[slice][t & 15] = sn; rD[slice][t & 15] = sd;
  __syncthreads();
  if (t < 16) {
    float2 n = rN[0][t], d = rD[0][t];
#pragma unroll
    for (int s = 1; s < 16; s++) {
      n.x += rN[s][t].x; n.y += rN[s][t].y;
      d.x += rD[s][t].x; d.y += rD[s][t].y;
    }
    int kk = idx >> 11, j = idx & (J_-1);
    float* vtf = (float*)g_Vt4;
    float v0 = vtf[j*16 + kk], v1 = vtf[j*16 + 8 + kk];
    vtf[j*16 + kk]     = v0 * sqrtf(n.x/d.x);
    vtf[j*16 + 8 + kk] = v1 * sqrtf(n.y/d.y);
  }
}

// ---------- final: fused D-accum + solve + Y = W · Xc output ----------
__global__ __launch_bounds__(256) void k_yout(float* __restrict__ out, int cplx) {
  int i = blockIdx.x, t = threadIdx.x;
  int wv = t >> 6, lane = t & 63;
  __shared__ float redD[4][12];
  __shared__ float2 sW[4];

  float2 tk2[K_];
#pragma unroll
  for (int k = 0; k < K_; k++) tk2[k] = g_T2[(size_t)i*K_ + k];

  {  // phase 1: D moments (final T,V)
    float4 xv[8];
#pragma unroll
    for (int s = 0; s < 8; s++) xv[s] = g_Xc[(size_t)i*J_ + wv*512 + s*64 + lane];
    float acc[12];
#pragma unroll
    for (int q = 0; q < 12; q++) acc[q] = 0.f;
#pragma unroll
    for (int s = 0; s < 8; s++) {
      int j = wv*512 + s*64 + lane;
      float4 vt0 = g_Vt4[(size_t)j*4+0], vt1 = g_Vt4[(size_t)j*4+1];
      float4 vt2 = g_Vt4[(size_t)j*4+2], vt3 = g_Vt4[(size_t)j*4+3];
      float vkx[K_] = {vt0.x,vt0.y,vt0.z,vt0.w,vt1.x,vt1.y,vt1.z,vt1.w};
      float vky[K_] = {vt2.x,vt2.y,vt2.z,vt2.w,vt3.x,vt3.y,vt3.z,vt3.w};
      float rn0 = 0.f, rn1 = 0.f;
#pragma unroll
      for (int k = 0; k < K_; k++) {
        rn0 = fmaf(tk2[k].x, vkx[k], rn0);
        rn1 = fmaf(tk2[k].y, vky[k], rn1);
      }
      float a0 = xv[s].x, b0 = xv[s].y, a1 = xv[s].z, b1 = xv[s].w;
      float d00r = a0*a0 - b0*b0, d00i = 2.f*a0*b0;
      float d01r = a0*a1 - b0*b1, d01i = a0*b1 + a1*b0;
      float d11r = a1*a1 - b1*b1, d11i = 2.f*a1*b1;
      float inv0 = frcp(rn0), inv1 = frcp(rn1);
      acc[0] = fmaf(d00r, inv0, acc[0]); acc[1] = fmaf(d00i, inv0, acc[1]);
      acc[2] = fmaf(d01r, inv0, acc[2]); acc[3] = fmaf(d01i, inv0, acc[3]);
      acc[4] = fmaf(d11r, inv0, acc[4]); acc[5] = fmaf(d11i, inv0, acc[5]);
      acc[6] = fmaf(d00r, inv1, acc[6]); acc[7] = fmaf(d00i, inv1, acc[7]);
      acc[8] = fmaf(d01r, inv1, acc[8]); acc[9] = fmaf(d01i, inv1, acc[9]);
      acc[10]= fmaf(d11r, inv1, acc[10]);acc[11]= fmaf(d11i, inv1, acc[11]);
    }
#pragma unroll
    for (int q = 0; q < 12; q++)
      for (int off = 32; off; off >>= 1) acc[q] += __shfl_down(acc[q], off);
    if (lane == 0) {
#pragma unroll
      for (int q = 0; q < 12; q++) redD[wv][q] = acc[q];
    }
  }
  __syncthreads();
  if (t == 0) {
    double s_[12];
#pragma unroll
    for (int q = 0; q < 12; q++)
      s_[q] = (double)redD[0][q] + (double)redD[1][q] + (double)redD[2][q] + (double)redD[3][q];
    float2 w[4];
    solve12(i, s_, w);
    sW[0] = w[0]; sW[1] = w[1]; sW[2] = w[2]; sW[3] = w[3];
  }
  __syncthreads();
  float2 w00 = sW[0], w01 = sW[1], w10 = sW[2], w11 = sW[3];
  float2* out2 = (float2*)out;
#pragma unroll
  for (int s = 0; s < 8; s++) {
    int j = t + 256*s;
    float4 xv = g_Xc[(size_t)i*J_ + j];
    float2 x0 = make_float2(xv.x, xv.y);
    float2 x1 = make_float2(xv.z, xv.w);
    float2 y0 = cyn(w00, w01, x0, x1);
    float2 y1 = cyn(w10, w11, x0, x1);
    if (cplx) {
      out2[((size_t)i*N_ + 0)*J_ + j] = y0;
      out2[((size_t)i*N_ + 1)*J_ + j] = y1;
    } else {      // float32(complex) == real part
      out[((size_t)i*N_ + 0)*J_ + j] = y0.x;
      out[((size_t)i*N_ + 1)*J_ + j] = y1.x;
    }
  }
}

extern "C" void kernel_launch(void* const* d_in, const int* in_sizes, int n_in,
                              void* d_out, int out_size, void* d_ws, size_t ws_size,
                              hipStream_t stream) {
  const float* X  = (const float*)d_in[0];
  const float* T0 = (const float*)d_in[1];
  const float* V0 = (const float*)d_in[2];
  (void)d_ws; (void)ws_size;

  k_setup<<<(I_*K_ + 255)/256, 256, 0, stream>>>(T0, V0);
  k_transpose<<<dim3((I_ + 63)/64, J_/32), 256, 0, stream>>>(X);

  int cplx = (out_size >= 2*I_*N_*J_) ? 1 : 0;
  for (int it = 0; it < NITER; it++) {
    // it>0: k_tv solves W(it) in-block from its own D phase (prev iter's T,V), then T-update
    k_tv<<<I_, 256, 0, stream>>>(it > 0);
    k_vupd2<<<dim3(J_/256, NCHUNK), 256, 0, stream>>>();
    k_vapply2<<<K_*J_/16, 256, 0, stream>>>();
  }
  k_yout<<<I_, 256, 0, stream>>>((float*)d_out, cplx);   // fused final D + solve + Y
}

// Round 8
// 542.929 us; speedup vs baseline: 1.1937x; 1.1264x over previous
//
#include <hip/hip_runtime.h>
#include <math.h>

#define I_  2049
#define J_  2048
#define K_  8
#define N_  2
#define NITER 5
#define EPSF 1e-20f
#define INVJ (1.0/2048.0)
#define CHUNK 16
#define NCHUNK 129  // ceil(2049/16)

// ---------- static device-global state ----------
__device__ float4 g_Xc[(size_t)I_*J_];      // 67 MB: Xc(I,J,M) — both m of a j in one float4
__device__ float  g_Tt[I_*16];              // T transposed: [i][n][k] (n-major, k in float4 groups)
__device__ float  g_Toldt[I_*16];           // start-of-iter snapshot, same layout
__device__ float4 g_Vt4[(size_t)J_*4];      // V transposed: [j][n][k] as 4x float4 per j
__device__ float2 g_W[I_*4];                // W[i][r][c]
__device__ float2 g_Wold[I_*4];             // iteration-start snapshot
__device__ float4 g_pnA[(size_t)NCHUNK*2*J_];   // V-update partials: num n0, [c][kg][j]
__device__ float4 g_pnB[(size_t)NCHUNK*2*J_];   // num n1
__device__ float4 g_pdA[(size_t)NCHUNK*2*J_];   // den n0
__device__ float4 g_pdB[(size_t)NCHUNK*2*J_];   // den n1

__device__ __forceinline__ float frcp(float x) { return __builtin_amdgcn_rcpf(x); }

__device__ __forceinline__ float dot44(float4 a, float4 b) {
  return fmaf(a.x, b.x, fmaf(a.y, b.y, fmaf(a.z, b.z, a.w*b.w)));
}
__device__ __forceinline__ float4 f4fma(float s, float4 v, float4 a) {
  a.x = fmaf(s, v.x, a.x); a.y = fmaf(s, v.y, a.y);
  a.z = fmaf(s, v.z, a.z); a.w = fmaf(s, v.w, a.w);
  return a;
}
__device__ __forceinline__ float4 f4add(float4 a, float4 b) {
  return make_float4(a.x+b.x, a.y+b.y, a.z+b.z, a.w+b.w);
}
__device__ __forceinline__ float4 wred4(float4 v) {
  v.x += __shfl_down(v.x,32); v.y += __shfl_down(v.y,32); v.z += __shfl_down(v.z,32); v.w += __shfl_down(v.w,32);
  v.x += __shfl_down(v.x,16); v.y += __shfl_down(v.y,16); v.z += __shfl_down(v.z,16); v.w += __shfl_down(v.w,16);
  v.x += __shfl_down(v.x, 8); v.y += __shfl_down(v.y, 8); v.z += __shfl_down(v.z, 8); v.w += __shfl_down(v.w, 8);
  v.x += __shfl_down(v.x, 4); v.y += __shfl_down(v.y, 4); v.z += __shfl_down(v.z, 4); v.w += __shfl_down(v.w, 4);
  v.x += __shfl_down(v.x, 2); v.y += __shfl_down(v.y, 2); v.z += __shfl_down(v.z, 2); v.w += __shfl_down(v.w, 2);
  v.x += __shfl_down(v.x, 1); v.y += __shfl_down(v.y, 1); v.z += __shfl_down(v.z, 1); v.w += __shfl_down(v.w, 1);
  return v;
}
#define RW(x) { x += __shfl_down(x,32); x += __shfl_down(x,16); x += __shfl_down(x,8); \
                x += __shfl_down(x,4);  x += __shfl_down(x,2);  x += __shfl_down(x,1); }

// ---------- double-complex helpers (per-i 2x2 solve only) ----------
struct dcx { double x, y; };
__device__ __forceinline__ dcx cmul(dcx a, dcx b) { return {a.x*b.x - a.y*b.y, a.x*b.y + a.y*b.x}; }
__device__ __forceinline__ dcx cadd(dcx a, dcx b) { return {a.x + b.x, a.y + b.y}; }
__device__ __forceinline__ dcx csub(dcx a, dcx b) { return {a.x - b.x, a.y - b.y}; }
__device__ __forceinline__ dcx cneg(dcx a) { return {-a.x, -a.y}; }
__device__ __forceinline__ dcx cdiv(dcx a, dcx b) {
  double d = b.x*b.x + b.y*b.y;
  return {(a.x*b.x + a.y*b.y)/d, (a.y*b.x - a.x*b.y)/d};
}
__device__ __forceinline__ dcx csqrt_(dcx z) {   // principal branch, numpy-compatible
  double r = hypot(z.x, z.y);
  if (r == 0.0) return {0.0, 0.0};
  double t = sqrt(0.5*(r + fabs(z.x)));
  if (z.x >= 0.0) return {t, z.y/(2.0*t)};
  return {fabs(z.y)/(2.0*t), (z.y >= 0.0) ? t : -t};
}

__device__ __forceinline__ float2 cyn(float2 w0, float2 w1, float2 x0, float2 x1) {
  float2 y;
  y.x = w0.x*x0.x - w0.y*x0.y + w1.x*x1.x - w1.y*x1.y;
  y.y = w0.x*x0.y + w0.y*x0.x + w1.x*x1.y + w1.y*x1.x;
  return y;
}

// ---------- per-i 2x2 solve (double) from 12 summed moments; writes g_W/g_Wold ----------
__device__ __forceinline__ void solve12(int i, const double* s_, float2* wout) {
  dcx Wl[2][2];
  Wl[0][0] = {g_W[(size_t)i*4+0].x, g_W[(size_t)i*4+0].y};
  Wl[0][1] = {g_W[(size_t)i*4+1].x, g_W[(size_t)i*4+1].y};
  Wl[1][0] = {g_W[(size_t)i*4+2].x, g_W[(size_t)i*4+2].y};
  Wl[1][1] = {g_W[(size_t)i*4+3].x, g_W[(size_t)i*4+3].y};
#pragma unroll
  for (int n = 0; n < N_; n++) {
    dcx D00 = {s_[6*n+0]*INVJ, s_[6*n+1]*INVJ};
    dcx D01 = {s_[6*n+2]*INVJ, s_[6*n+3]*INVJ};
    dcx D11 = {s_[6*n+4]*INVJ, s_[6*n+5]*INVJ};
    dcx WD00 = cadd(cmul(Wl[0][0], D00), cmul(Wl[0][1], D01));
    dcx WD01 = cadd(cmul(Wl[0][0], D01), cmul(Wl[0][1], D11));
    dcx WD10 = cadd(cmul(Wl[1][0], D00), cmul(Wl[1][1], D01));
    dcx WD11 = cadd(cmul(Wl[1][0], D01), cmul(Wl[1][1], D11));
    dcx det = csub(cmul(WD00, WD11), cmul(WD01, WD10));
    dcx b0, b1;
    if (n == 0) { b0 = cdiv(WD11, det);        b1 = cdiv(cneg(WD10), det); }
    else        { b0 = cdiv(cneg(WD01), det);  b1 = cdiv(WD00, det); }
    dcx nrm = cadd(cmul(cmul(b0, b0), D00), cmul(cmul(b1, b1), D11));
    dcx tcr = cmul(cmul(b0, b1), D01); tcr.x *= 2.0; tcr.y *= 2.0;
    nrm = cadd(nrm, tcr);
    dcx sq = csqrt_(nrm);
    Wl[0][n] = cdiv(b0, sq);
    Wl[1][n] = cdiv(b1, sq);
  }
  float2 o00 = make_float2((float)Wl[0][0].x, (float)Wl[0][0].y);
  float2 o01 = make_float2((float)Wl[0][1].x, (float)Wl[0][1].y);
  float2 o10 = make_float2((float)Wl[1][0].x, (float)Wl[1][0].y);
  float2 o11 = make_float2((float)Wl[1][1].x, (float)Wl[1][1].y);
  g_W[(size_t)i*4+0] = o00; g_W[(size_t)i*4+1] = o01;
  g_W[(size_t)i*4+2] = o10; g_W[(size_t)i*4+3] = o11;
  g_Wold[(size_t)i*4+0] = o00; g_Wold[(size_t)i*4+1] = o01;
  g_Wold[(size_t)i*4+2] = o10; g_Wold[(size_t)i*4+3] = o11;
  wout[0] = o00; wout[1] = o01; wout[2] = o10; wout[3] = o11;
}

// ---------- setup: Tt<-T0 (transposed), Vt<-V0 (transposed), W=Wold=eye ----------
// NOTE: grid must cover I_*K_ = 16392 (> K_*J_ = 16384): 65 blocks.
__global__ __launch_bounds__(256) void k_setup(const float* __restrict__ T0,
                                               const float* __restrict__ V0) {
  int idx = blockIdx.x*256 + threadIdx.x;
  if (idx < I_*K_) {
    int i = idx >> 3, k = idx & 7;
    float2 v = ((const float2*)T0)[idx];
    g_Tt[i*16 + k]     = v.x;   // n=0
    g_Tt[i*16 + 8 + k] = v.y;   // n=1
  }
  if (idx < K_*J_) {
    int k = idx >> 11, j = idx & (J_-1);
    float2 v = ((const float2*)V0)[idx];
    float* vtf = (float*)g_Vt4;
    vtf[j*16 + k]     = v.x;   // n=0
    vtf[j*16 + 8 + k] = v.y;   // n=1
  }
  if (idx < I_*4) {
    int r = (idx >> 1) & 1, c = idx & 1;
    float2 v = make_float2((r == c) ? 1.f : 0.f, 0.f);
    g_W[idx] = v;
    g_Wold[idx] = v;
  }
}

// ---------- transpose X(M,J,I,2) -> g_Xc(I,J,M); both m fused, float4 writes ----------
__global__ __launch_bounds__(256) void k_transpose(const float* __restrict__ X) {
  __shared__ float2 s0[32][65];   // [jj][ii], m=0
  __shared__ float2 s1[32][65];   // m=1
  int i0 = blockIdx.x*64, j0 = blockIdx.y*32;
  int lane = threadIdx.x & 63, row = threadIdx.x >> 6;
  const float2* X2 = (const float2*)X;   // (m*J + j)*I + i
  int gi = i0 + lane;
  if (gi < I_) {
    for (int jj = row; jj < 32; jj += 4) {
      s0[jj][lane] = X2[(size_t)(0*J_ + j0 + jj)*I_ + gi];
      s1[jj][lane] = X2[(size_t)(1*J_ + j0 + jj)*I_ + gi];
    }
  }
  __syncthreads();
  int jj = threadIdx.x & 31, ii0 = threadIdx.x >> 5;   // 32 lanes = 32 consecutive j (512B line)
  for (int u = 0; u < 8; u++) {
    int ii = ii0*8 + u;
    int i = i0 + ii;
    if (i < I_) {
      float2 a = s0[jj][ii], b = s1[jj][ii];
      g_Xc[(size_t)i*J_ + j0 + jj] = make_float4(a.x, a.y, b.x, b.y);
    }
  }
}

// ---------- fused per-i kernel: [D-accum + mid-block solve] (doD) + T-update ----------
// All per-thread state in NAMED scalars/float4s — nothing the compiler can LDS-promote.
__global__ __launch_bounds__(256, 2) void k_tv(int doD) {
  int i = blockIdx.x, t = threadIdx.x;
  int wv = t >> 6, lane = t & 63;
  __shared__ float redD[4][12];
  __shared__ float2 sW[4];
  __shared__ float redT[4][32];

  const float4* T4 = (const float4*)g_Tt;
  float4 tt0 = T4[i*4+0], tt1 = T4[i*4+1];   // n=0: k0-3, k4-7
  float4 tt2 = T4[i*4+2], tt3 = T4[i*4+3];   // n=1

  if (doD) {
    // ---- phase 1: D moments over this wave's 512-j slice ----
    size_t xb = (size_t)i*J_ + wv*512 + lane;
    float4 xv0 = g_Xc[xb+0*64], xv1 = g_Xc[xb+1*64], xv2 = g_Xc[xb+2*64], xv3 = g_Xc[xb+3*64];
    float4 xv4 = g_Xc[xb+4*64], xv5 = g_Xc[xb+5*64], xv6 = g_Xc[xb+6*64], xv7 = g_Xc[xb+7*64];
    float s0=0.f,s1=0.f,s2=0.f,s3=0.f,s4=0.f,s5=0.f,s6=0.f,s7=0.f,s8=0.f,s9=0.f,s10=0.f,s11=0.f;
#define DB(U) { int j = wv*512 + U*64 + lane; \
    const float4* Vp = g_Vt4 + (size_t)j*4; \
    float4 vt0=Vp[0], vt1=Vp[1], vt2=Vp[2], vt3=Vp[3]; \
    float rn0 = dot44(tt0,vt0)+dot44(tt1,vt1); \
    float rn1 = dot44(tt2,vt2)+dot44(tt3,vt3); \
    float a0=xv##U.x, b0=xv##U.y, a1=xv##U.z, b1=xv##U.w; \
    float e00r=a0*a0-b0*b0, e00i=2.f*a0*b0; \
    float e01r=a0*a1-b0*b1, e01i=a0*b1+a1*b0; \
    float e11r=a1*a1-b1*b1, e11i=2.f*a1*b1; \
    float inv0=frcp(rn0), inv1=frcp(rn1); \
    s0=fmaf(e00r,inv0,s0);  s1=fmaf(e00i,inv0,s1); \
    s2=fmaf(e01r,inv0,s2);  s3=fmaf(e01i,inv0,s3); \
    s4=fmaf(e11r,inv0,s4);  s5=fmaf(e11i,inv0,s5); \
    s6=fmaf(e00r,inv1,s6);  s7=fmaf(e00i,inv1,s7); \
    s8=fmaf(e01r,inv1,s8);  s9=fmaf(e01i,inv1,s9); \
    s10=fmaf(e11r,inv1,s10); s11=fmaf(e11i,inv1,s11); }
    DB(0) DB(1) DB(2) DB(3) DB(4) DB(5) DB(6) DB(7)
#undef DB
    RW(s0) RW(s1) RW(s2) RW(s3) RW(s4) RW(s5) RW(s6) RW(s7) RW(s8) RW(s9) RW(s10) RW(s11)
    if (lane == 0) {
      redD[wv][0]=s0;  redD[wv][1]=s1;  redD[wv][2]=s2;  redD[wv][3]=s3;
      redD[wv][4]=s4;  redD[wv][5]=s5;  redD[wv][6]=s6;  redD[wv][7]=s7;
      redD[wv][8]=s8;  redD[wv][9]=s9;  redD[wv][10]=s10; redD[wv][11]=s11;
    }
    __syncthreads();
    if (t == 0) {
      double s_[12];
#pragma unroll
      for (int q = 0; q < 12; q++)
        s_[q] = (double)redD[0][q] + (double)redD[1][q] + (double)redD[2][q] + (double)redD[3][q];
      float2 w[4];
      solve12(i, s_, w);
      sW[0] = w[0]; sW[1] = w[1]; sW[2] = w[2]; sW[3] = w[3];
    }
  } else {
    if (t == 0) {
      sW[0] = g_Wold[(size_t)i*4+0]; sW[1] = g_Wold[(size_t)i*4+1];
      sW[2] = g_Wold[(size_t)i*4+2]; sW[3] = g_Wold[(size_t)i*4+3];
    }
  }
  __syncthreads();
  float2 w00 = sW[0], w01 = sW[1], w10 = sW[2], w11 = sW[3];

  // ---- phase 2: T update (row is L2/L3-hot when doD) ----
  size_t yb = (size_t)i*J_ + t;
  float4 xw0 = g_Xc[yb+0*256], xw1 = g_Xc[yb+1*256], xw2 = g_Xc[yb+2*256], xw3 = g_Xc[yb+3*256];
  float4 xw4 = g_Xc[yb+4*256], xw5 = g_Xc[yb+5*256], xw6 = g_Xc[yb+6*256], xw7 = g_Xc[yb+7*256];
  float4 z = make_float4(0.f,0.f,0.f,0.f);
  float4 aN0a=z, aN0b=z, aD0a=z, aD0b=z, aN1a=z, aN1b=z, aD1a=z, aD1b=z;
#define TB(U) { int j = t + U*256; \
  const float4* Vp = g_Vt4 + (size_t)j*4; \
  float4 vt0=Vp[0], vt1=Vp[1], vt2=Vp[2], vt3=Vp[3]; \
  float rn0 = dot44(tt0,vt0)+dot44(tt1,vt1); \
  float rn1 = dot44(tt2,vt2)+dot44(tt3,vt3); \
  float2 x0=make_float2(xw##U.x,xw##U.y), x1=make_float2(xw##U.z,xw##U.w); \
  float2 y0=cyn(w00,w01,x0,x1), y1=cyn(w10,w11,x0,x1); \
  float p0=(y0.x*y0.x+y0.y*y0.y)*frcp(rn0*rn0+EPSF); \
  float p1=(y1.x*y1.x+y1.y*y1.y)*frcp(rn1*rn1+EPSF); \
  float rd0=frcp(rn0), rd1=frcp(rn1); \
  aN0a=f4fma(p0,vt0,aN0a); aN0b=f4fma(p0,vt1,aN0b); \
  aD0a=f4fma(rd0,vt0,aD0a); aD0b=f4fma(rd0,vt1,aD0b); \
  aN1a=f4fma(p1,vt2,aN1a); aN1b=f4fma(p1,vt3,aN1b); \
  aD1a=f4fma(rd1,vt2,aD1a); aD1b=f4fma(rd1,vt3,aD1b); }
  TB(0) TB(1) TB(2) TB(3) TB(4) TB(5) TB(6) TB(7)
#undef TB
  aN0a = wred4(aN0a); aN0b = wred4(aN0b); aD0a = wred4(aD0a); aD0b = wred4(aD0b);
  aN1a = wred4(aN1a); aN1b = wred4(aN1b); aD1a = wred4(aD1a); aD1b = wred4(aD1b);
  if (lane == 0) {
    redT[wv][0]=aN0a.x;  redT[wv][1]=aN0a.y;  redT[wv][2]=aN0a.z;  redT[wv][3]=aN0a.w;
    redT[wv][4]=aN0b.x;  redT[wv][5]=aN0b.y;  redT[wv][6]=aN0b.z;  redT[wv][7]=aN0b.w;
    redT[wv][8]=aD0a.x;  redT[wv][9]=aD0a.y;  redT[wv][10]=aD0a.z; redT[wv][11]=aD0a.w;
    redT[wv][12]=aD0b.x; redT[wv][13]=aD0b.y; redT[wv][14]=aD0b.z; redT[wv][15]=aD0b.w;
    redT[wv][16]=aN1a.x; redT[wv][17]=aN1a.y; redT[wv][18]=aN1a.z; redT[wv][19]=aN1a.w;
    redT[wv][20]=aN1b.x; redT[wv][21]=aN1b.y; redT[wv][22]=aN1b.z; redT[wv][23]=aN1b.w;
    redT[wv][24]=aD1a.x; redT[wv][25]=aD1a.y; redT[wv][26]=aD1a.z; redT[wv][27]=aD1a.w;
    redT[wv][28]=aD1b.x; redT[wv][29]=aD1b.y; redT[wv][30]=aD1b.z; redT[wv][31]=aD1b.w;
  }
  __syncthreads();
  if (t < 8) {
    int k = t;
    float n0 = redT[0][k]    + redT[1][k]    + redT[2][k]    + redT[3][k];
    float d0 = redT[0][8+k]  + redT[1][8+k]  + redT[2][8+k]  + redT[3][8+k];
    float n1 = redT[0][16+k] + redT[1][16+k] + redT[2][16+k] + redT[3][16+k];
    float d1 = redT[0][24+k] + redT[1][24+k] + redT[2][24+k] + redT[3][24+k];
    float tvx = g_Tt[i*16 + k], tvy = g_Tt[i*16 + 8 + k];
    g_Toldt[i*16 + k]     = tvx;
    g_Toldt[i*16 + 8 + k] = tvy;
    g_Tt[i*16 + k]     = tvx * sqrtf(n0/d0);
    g_Tt[i*16 + 8 + k] = tvy * sqrtf(n1/d1);
  }
}

// ---------- V partial accumulation; float4 T/Told from LDS; named accumulators ----------
__global__ __launch_bounds__(256, 2) void k_vupd2() {
  int t  = threadIdx.x;
  int j  = blockIdx.x*256 + t;
  int c  = blockIdx.y;
  int i0 = c*CHUNK;
  int ni = I_ - i0; if (ni > CHUNK) ni = CHUNK;

  __shared__ float2 sWold[CHUNK*4];
  __shared__ float4 sTold[CHUNK*4];
  __shared__ float4 sT[CHUNK*4];
  const float4* To4 = (const float4*)g_Toldt;
  const float4* Tn4 = (const float4*)g_Tt;
  if (t < CHUNK*4) {
    int g = i0*4 + t; if (g < I_*4) sWold[t] = g_Wold[g];
  } else if (t < CHUNK*8) {
    int u = t - CHUNK*4; int g = i0*4 + u; if (g < I_*4) sTold[u] = To4[g];
  } else if (t < CHUNK*12) {
    int u = t - CHUNK*8; int g = i0*4 + u; if (g < I_*4) sT[u] = Tn4[g];
  }
  __syncthreads();

  const float4* Vp = g_Vt4 + (size_t)j*4;
  float4 vt0 = Vp[0], vt1 = Vp[1], vt2 = Vp[2], vt3 = Vp[3];
  float4 z = make_float4(0.f,0.f,0.f,0.f);
  float4 aN0a=z, aN0b=z, aD0a=z, aD0b=z, aN1a=z, aN1b=z, aD1a=z, aD1b=z;

  auto body = [&](int ii, float4 xv) {
    float2 x0 = make_float2(xv.x, xv.y), x1 = make_float2(xv.z, xv.w);
    float2 w00 = sWold[ii*4+0], w01 = sWold[ii*4+1], w10 = sWold[ii*4+2], w11 = sWold[ii*4+3];
    float4 to0 = sTold[ii*4+0], to1 = sTold[ii*4+1], to2 = sTold[ii*4+2], to3 = sTold[ii*4+3];
    float rn0 = dot44(to0,vt0)+dot44(to1,vt1);
    float rn1 = dot44(to2,vt2)+dot44(to3,vt3);
    float2 y0 = cyn(w00,w01,x0,x1), y1 = cyn(w10,w11,x0,x1);
    float p0 = (y0.x*y0.x+y0.y*y0.y)*frcp(rn0*rn0+EPSF);
    float p1 = (y1.x*y1.x+y1.y*y1.y)*frcp(rn1*rn1+EPSF);
    float rd0 = frcp(rn0), rd1 = frcp(rn1);
    float4 st0 = sT[ii*4+0], st1 = sT[ii*4+1], st2 = sT[ii*4+2], st3 = sT[ii*4+3];
    aN0a = f4fma(p0,  st0, aN0a); aN0b = f4fma(p0,  st1, aN0b);
    aD0a = f4fma(rd0, st0, aD0a); aD0b = f4fma(rd0, st1, aD0b);
    aN1a = f4fma(p1,  st2, aN1a); aN1b = f4fma(p1,  st3, aN1b);
    aD1a = f4fma(rd1, st2, aD1a); aD1b = f4fma(rd1, st3, aD1b);
  };

  int ii = 0;
  for (; ii + 8 <= ni; ii += 8) {
    float4 xA = g_Xc[(size_t)(i0+ii+0)*J_ + j];
    float4 xB = g_Xc[(size_t)(i0+ii+1)*J_ + j];
    float4 xC = g_Xc[(size_t)(i0+ii+2)*J_ + j];
    float4 xD = g_Xc[(size_t)(i0+ii+3)*J_ + j];
    float4 xE = g_Xc[(size_t)(i0+ii+4)*J_ + j];
    float4 xF = g_Xc[(size_t)(i0+ii+5)*J_ + j];
    float4 xG = g_Xc[(size_t)(i0+ii+6)*J_ + j];
    float4 xH = g_Xc[(size_t)(i0+ii+7)*J_ + j];
    body(ii+0,xA); body(ii+1,xB); body(ii+2,xC); body(ii+3,xD);
    body(ii+4,xE); body(ii+5,xF); body(ii+6,xG); body(ii+7,xH);
  }
  for (; ii < ni; ii++) body(ii, g_Xc[(size_t)(i0+ii)*J_ + j]);

  size_t b2 = (size_t)c*2*J_;
  g_pnA[b2 + j] = aN0a;  g_pnA[b2 + J_ + j] = aN0b;
  g_pnB[b2 + j] = aN1a;  g_pnB[b2 + J_ + j] = aN1b;
  g_pdA[b2 + j] = aD0a;  g_pdA[b2 + J_ + j] = aD0b;
  g_pdB[b2 + j] = aD1a;  g_pdB[b2 + J_ + j] = aD1b;
}

// ---------- chunk-reduce partials + apply Vt *= sqrt(num/den); float4 wide ----------
__global__ __launch_bounds__(256) void k_vapply2() {
  int t = threadIdx.x;
  int g = blockIdx.x*16 + (t & 15);         // (kg,j) group: kg = g>>11, j = g&2047
  int slice = t >> 4;                       // 16 c-slices of 9 (16*9=144 >= 129)
  int kg = g >> 11, j = g & (J_-1);
  int c0 = slice*9, c1 = c0 + 9; if (c1 > NCHUNK) c1 = NCHUNK;
  float4 z = make_float4(0.f,0.f,0.f,0.f);
  float4 sNa=z, sNb=z, sDa=z, sDb=z;
  for (int c = c0; c < c1; c++) {
    size_t o = (size_t)c*2*J_ + (size_t)kg*J_ + j;
    sNa = f4add(sNa, g_pnA[o]); sNb = f4add(sNb, g_pnB[o]);
    sDa = f4add(sDa, g_pdA[o]); sDb = f4add(sDb, g_pdB[o]);
  }
  __shared__ float4 rNa[16][16], rNb[16][16], rDa[16][16], rDb[16][16];
  rNa[slice][t & 15] = sNa; rNb[slice][t & 15] = sNb;
  rDa[slice][t & 15] = sDa; rDb[slice][t & 15] = sDb;
  __syncthreads();
  if (t < 16) {
    float4 na = rNa[0][t], nb = rNb[0][t], da = rDa[0][t], db = rDb[0][t];
#pragma unroll
    for (int s = 1; s < 16; s++) {
      na = f4add(na, rNa[s][t]); nb = f4add(nb, rNb[s][t]);
      da = f4add(da, rDa[s][t]); db = f4add(db, rDb[s][t]);
    }
    int gg = blockIdx.x*16 + t;
    int kg2 = gg >> 11, j2 = gg & (J_-1);
    float4 v0 = g_Vt4[(size_t)j2*4 + kg2];       // n=0, k-group kg2
    float4 v1 = g_Vt4[(size_t)j2*4 + 2 + kg2];   // n=1
    v0.x *= sqrtf(na.x/da.x); v0.y *= sqrtf(na.y/da.y); v0.z *= sqrtf(na.z/da.z); v0.w *= sqrtf(na.w/da.w);
    v1.x *= sqrtf(nb.x/db.x); v1.y *= sqrtf(nb.y/db.y); v1.z *= sqrtf(nb.z/db.z); v1.w *= sqrtf(nb.w/db.w);
    g_Vt4[(size_t)j2*4 + kg2] = v0;
    g_Vt4[(size_t)j2*4 + 2 + kg2] = v1;
  }
}

// ---------- final: fused D-accum + solve + Y = W · Xc output ----------
__global__ __launch_bounds__(256, 2) void k_yout(float* __restrict__ out, int cplx) {
  int i = blockIdx.x, t = threadIdx.x;
  int wv = t >> 6, lane = t & 63;
  __shared__ float redD[4][12];
  __shared__ float2 sW[4];

  const float4* T4 = (const float4*)g_Tt;
  float4 tt0 = T4[i*4+0], tt1 = T4[i*4+1], tt2 = T4[i*4+2], tt3 = T4[i*4+3];

  {
    size_t xb = (size_t)i*J_ + wv*512 + lane;
    float4 xv0 = g_Xc[xb+0*64], xv1 = g_Xc[xb+1*64], xv2 = g_Xc[xb+2*64], xv3 = g_Xc[xb+3*64];
    float4 xv4 = g_Xc[xb+4*64], xv5 = g_Xc[xb+5*64], xv6 = g_Xc[xb+6*64], xv7 = g_Xc[xb+7*64];
    float s0=0.f,s1=0.f,s2=0.f,s3=0.f,s4=0.f,s5=0.f,s6=0.f,s7=0.f,s8=0.f,s9=0.f,s10=0.f,s11=0.f;
#define DB(U) { int j = wv*512 + U*64 + lane; \
    const float4* Vp = g_Vt4 + (size_t)j*4; \
    float4 vt0=Vp[0], vt1=Vp[1], vt2=Vp[2], vt3=Vp[3]; \
    float rn0 = dot44(tt0,vt0)+dot44(tt1,vt1); \
    float rn1 = dot44(tt2,vt2)+dot44(tt3,vt3); \
    float a0=xv##U.x, b0=xv##U.y, a1=xv##U.z, b1=xv##U.w; \
    float e00r=a0*a0-b0*b0, e00i=2.f*a0*b0; \
    float e01r=a0*a1-b0*b1, e01i=a0*b1+a1*b0; \
    float e11r=a1*a1-b1*b1, e11i=2.f*a1*b1; \
    float inv0=frcp(rn0), inv1=frcp(rn1); \
    s0=fmaf(e00r,inv0,s0);  s1=fmaf(e00i,inv0,s1); \
    s2=fmaf(e01r,inv0,s2);  s3=fmaf(e01i,inv0,s3); \
    s4=fmaf(e11r,inv0,s4);  s5=fmaf(e11i,inv0,s5); \
    s6=fmaf(e00r,inv1,s6);  s7=fmaf(e00i,inv1,s7); \
    s8=fmaf(e01r,inv1,s8);  s9=fmaf(e01i,inv1,s9); \
    s10=fmaf(e11r,inv1,s10); s11=fmaf(e11i,inv1,s11); }
    DB(0) DB(1) DB(2) DB(3) DB(4) DB(5) DB(6) DB(7)
#undef DB
    RW(s0) RW(s1) RW(s2) RW(s3) RW(s4) RW(s5) RW(s6) RW(s7) RW(s8) RW(s9) RW(s10) RW(s11)
    if (lane == 0) {
      redD[wv][0]=s0;  redD[wv][1]=s1;  redD[wv][2]=s2;  redD[wv][3]=s3;
      redD[wv][4]=s4;  redD[wv][5]=s5;  redD[wv][6]=s6;  redD[wv][7]=s7;
      redD[wv][8]=s8;  redD[wv][9]=s9;  redD[wv][10]=s10; redD[wv][11]=s11;
    }
  }
  __syncthreads();
  if (t == 0) {
    double s_[12];
#pragma unroll
    for (int q = 0; q < 12; q++)
      s_[q] = (double)redD[0][q] + (double)redD[1][q] + (double)redD[2][q] + (double)redD[3][q];
    float2 w[4];
    solve12(i, s_, w);
    sW[0] = w[0]; sW[1] = w[1]; sW[2] = w[2]; sW[3] = w[3];
  }
  __syncthreads();
  float2 w00 = sW[0], w01 = sW[1], w10 = sW[2], w11 = sW[3];
  float2* out2 = (float2*)out;
#pragma unroll
  for (int s = 0; s < 8; s++) {
    int j = t + 256*s;
    float4 xv = g_Xc[(size_t)i*J_ + j];
    float2 x0 = make_float2(xv.x, xv.y);
    float2 x1 = make_float2(xv.z, xv.w);
    float2 y0 = cyn(w00, w01, x0, x1);
    float2 y1 = cyn(w10, w11, x0, x1);
    if (cplx) {
      out2[((size_t)i*N_ + 0)*J_ + j] = y0;
      out2[((size_t)i*N_ + 1)*J_ + j] = y1;
    } else {      // float32(complex) == real part
      out[((size_t)i*N_ + 0)*J_ + j] = y0.x;
      out[((size_t)i*N_ + 1)*J_ + j] = y1.x;
    }
  }
}

extern "C" void kernel_launch(void* const* d_in, const int* in_sizes, int n_in,
                              void* d_out, int out_size, void* d_ws, size_t ws_size,
                              hipStream_t stream) {
  const float* X  = (const float*)d_in[0];
  const float* T0 = (const float*)d_in[1];
  const float* V0 = (const float*)d_in[2];
  (void)d_ws; (void)ws_size;

  // grid covers I_*K_ = 16392 (largest init domain) — 65 blocks
  k_setup<<<(I_*K_ + 255)/256, 256, 0, stream>>>(T0, V0);
  k_transpose<<<dim3((I_ + 63)/64, J_/32), 256, 0, stream>>>(X);

  int cplx = (out_size >= 2*I_*N_*J_) ? 1 : 0;
  for (int it = 0; it < NITER; it++) {
    // it>0: k_tv solves W(it) in-block from its own D phase (prev iter's T,V), then T-update
    k_tv<<<I_, 256, 0, stream>>>(it > 0);
    k_vupd2<<<dim3(J_/256, NCHUNK), 256, 0, stream>>>();
    k_vapply2<<<2*J_/16, 256, 0, stream>>>();
  }
  k_yout<<<I_, 256, 0, stream>>>((float*)d_out, cplx);   // fused final D + solve + Y
}

// Round 9
// 535.958 us; speedup vs baseline: 1.2092x; 1.0130x over previous
//
#include <hip/hip_runtime.h>
#include <math.h>

#define I_  2049
#define J_  2048
#define K_  8
#define N_  2
#define NITER 5
#define EPSF 1e-20f
#define INVJ (1.0/2048.0)
#define CHUNK 16
#define NCHUNK 129  // ceil(2049/16)

// ---------- static device-global state ----------
__device__ float4 g_Xc[(size_t)I_*J_];      // 67 MB: Xc(I,J,M) — both m of a j in one float4
__device__ float  g_Tt[I_*16];              // T transposed: [i][n][k] (n-major, k in float4 groups)
__device__ float  g_Toldt[I_*16];           // start-of-iter snapshot, same layout
__device__ float4 g_Vt4[(size_t)J_*4];      // V transposed: [j][n][k] as 4x float4 per j
__device__ float2 g_W[I_*4];                // W[i][r][c]
__device__ float2 g_Wold[I_*4];             // iteration-start snapshot
__device__ float4 g_pnA[(size_t)NCHUNK*2*J_];   // V-update partials: num n0, [c][kg][j]
__device__ float4 g_pnB[(size_t)NCHUNK*2*J_];   // num n1
__device__ float4 g_pdA[(size_t)NCHUNK*2*J_];   // den n0
__device__ float4 g_pdB[(size_t)NCHUNK*2*J_];   // den n1

__device__ __forceinline__ float frcp(float x) { return __builtin_amdgcn_rcpf(x); }

__device__ __forceinline__ float dot44(float4 a, float4 b) {
  return fmaf(a.x, b.x, fmaf(a.y, b.y, fmaf(a.z, b.z, a.w*b.w)));
}
__device__ __forceinline__ float4 f4fma(float s, float4 v, float4 a) {
  a.x = fmaf(s, v.x, a.x); a.y = fmaf(s, v.y, a.y);
  a.z = fmaf(s, v.z, a.z); a.w = fmaf(s, v.w, a.w);
  return a;
}
__device__ __forceinline__ float4 f4add(float4 a, float4 b) {
  return make_float4(a.x+b.x, a.y+b.y, a.z+b.z, a.w+b.w);
}
__device__ __forceinline__ float4 wred4(float4 v) {
  v.x += __shfl_down(v.x,32); v.y += __shfl_down(v.y,32); v.z += __shfl_down(v.z,32); v.w += __shfl_down(v.w,32);
  v.x += __shfl_down(v.x,16); v.y += __shfl_down(v.y,16); v.z += __shfl_down(v.z,16); v.w += __shfl_down(v.w,16);
  v.x += __shfl_down(v.x, 8); v.y += __shfl_down(v.y, 8); v.z += __shfl_down(v.z, 8); v.w += __shfl_down(v.w, 8);
  v.x += __shfl_down(v.x, 4); v.y += __shfl_down(v.y, 4); v.z += __shfl_down(v.z, 4); v.w += __shfl_down(v.w, 4);
  v.x += __shfl_down(v.x, 2); v.y += __shfl_down(v.y, 2); v.z += __shfl_down(v.z, 2); v.w += __shfl_down(v.w, 2);
  v.x += __shfl_down(v.x, 1); v.y += __shfl_down(v.y, 1); v.z += __shfl_down(v.z, 1); v.w += __shfl_down(v.w, 1);
  return v;
}
#define RW(x) { x += __shfl_down(x,32); x += __shfl_down(x,16); x += __shfl_down(x,8); \
                x += __shfl_down(x,4);  x += __shfl_down(x,2);  x += __shfl_down(x,1); }

// ---------- double-complex helpers (per-i 2x2 solve only) ----------
struct dcx { double x, y; };
__device__ __forceinline__ dcx cmul(dcx a, dcx b) { return {a.x*b.x - a.y*b.y, a.x*b.y + a.y*b.x}; }
__device__ __forceinline__ dcx cadd(dcx a, dcx b) { return {a.x + b.x, a.y + b.y}; }
__device__ __forceinline__ dcx csub(dcx a, dcx b) { return {a.x - b.x, a.y - b.y}; }
__device__ __forceinline__ dcx cneg(dcx a) { return {-a.x, -a.y}; }
__device__ __forceinline__ dcx cdiv(dcx a, dcx b) {
  double d = b.x*b.x + b.y*b.y;
  return {(a.x*b.x + a.y*b.y)/d, (a.y*b.x - a.x*b.y)/d};
}
__device__ __forceinline__ dcx csqrt_(dcx z) {   // principal branch, numpy-compatible
  double r = hypot(z.x, z.y);
  if (r == 0.0) return {0.0, 0.0};
  double t = sqrt(0.5*(r + fabs(z.x)));
  if (z.x >= 0.0) return {t, z.y/(2.0*t)};
  return {fabs(z.y)/(2.0*t), (z.y >= 0.0) ? t : -t};
}

__device__ __forceinline__ float2 cyn(float2 w0, float2 w1, float2 x0, float2 x1) {
  float2 y;
  y.x = w0.x*x0.x - w0.y*x0.y + w1.x*x1.x - w1.y*x1.y;
  y.y = w0.x*x0.y + w0.y*x0.x + w1.x*x1.y + w1.y*x1.x;
  return y;
}

// ---------- per-i 2x2 solve (double) from 12 summed moments; writes g_W/g_Wold ----------
__device__ __forceinline__ void solve12(int i, const double* s_, float2* wout) {
  dcx Wl[2][2];
  Wl[0][0] = {g_W[(size_t)i*4+0].x, g_W[(size_t)i*4+0].y};
  Wl[0][1] = {g_W[(size_t)i*4+1].x, g_W[(size_t)i*4+1].y};
  Wl[1][0] = {g_W[(size_t)i*4+2].x, g_W[(size_t)i*4+2].y};
  Wl[1][1] = {g_W[(size_t)i*4+3].x, g_W[(size_t)i*4+3].y};
#pragma unroll
  for (int n = 0; n < N_; n++) {
    dcx D00 = {s_[6*n+0]*INVJ, s_[6*n+1]*INVJ};
    dcx D01 = {s_[6*n+2]*INVJ, s_[6*n+3]*INVJ};
    dcx D11 = {s_[6*n+4]*INVJ, s_[6*n+5]*INVJ};
    dcx WD00 = cadd(cmul(Wl[0][0], D00), cmul(Wl[0][1], D01));
    dcx WD01 = cadd(cmul(Wl[0][0], D01), cmul(Wl[0][1], D11));
    dcx WD10 = cadd(cmul(Wl[1][0], D00), cmul(Wl[1][1], D01));
    dcx WD11 = cadd(cmul(Wl[1][0], D01), cmul(Wl[1][1], D11));
    dcx det = csub(cmul(WD00, WD11), cmul(WD01, WD10));
    dcx b0, b1;
    if (n == 0) { b0 = cdiv(WD11, det);        b1 = cdiv(cneg(WD10), det); }
    else        { b0 = cdiv(cneg(WD01), det);  b1 = cdiv(WD00, det); }
    dcx nrm = cadd(cmul(cmul(b0, b0), D00), cmul(cmul(b1, b1), D11));
    dcx tcr = cmul(cmul(b0, b1), D01); tcr.x *= 2.0; tcr.y *= 2.0;
    nrm = cadd(nrm, tcr);
    dcx sq = csqrt_(nrm);
    Wl[0][n] = cdiv(b0, sq);
    Wl[1][n] = cdiv(b1, sq);
  }
  float2 o00 = make_float2((float)Wl[0][0].x, (float)Wl[0][0].y);
  float2 o01 = make_float2((float)Wl[0][1].x, (float)Wl[0][1].y);
  float2 o10 = make_float2((float)Wl[1][0].x, (float)Wl[1][0].y);
  float2 o11 = make_float2((float)Wl[1][1].x, (float)Wl[1][1].y);
  g_W[(size_t)i*4+0] = o00; g_W[(size_t)i*4+1] = o01;
  g_W[(size_t)i*4+2] = o10; g_W[(size_t)i*4+3] = o11;
  g_Wold[(size_t)i*4+0] = o00; g_Wold[(size_t)i*4+1] = o01;
  g_Wold[(size_t)i*4+2] = o10; g_Wold[(size_t)i*4+3] = o11;
  wout[0] = o00; wout[1] = o01; wout[2] = o10; wout[3] = o11;
}

// ---------- setup: Tt<-T0 (transposed), Vt<-V0 (transposed), W=Wold=eye ----------
// NOTE: grid must cover I_*K_ = 16392 (> K_*J_ = 16384): 65 blocks.
__global__ __launch_bounds__(256) void k_setup(const float* __restrict__ T0,
                                               const float* __restrict__ V0) {
  int idx = blockIdx.x*256 + threadIdx.x;
  if (idx < I_*K_) {
    int i = idx >> 3, k = idx & 7;
    float2 v = ((const float2*)T0)[idx];
    g_Tt[i*16 + k]     = v.x;   // n=0
    g_Tt[i*16 + 8 + k] = v.y;   // n=1
  }
  if (idx < K_*J_) {
    int k = idx >> 11, j = idx & (J_-1);
    float2 v = ((const float2*)V0)[idx];
    float* vtf = (float*)g_Vt4;
    vtf[j*16 + k]     = v.x;   // n=0
    vtf[j*16 + 8 + k] = v.y;   // n=1
  }
  if (idx < I_*4) {
    int r = (idx >> 1) & 1, c = idx & 1;
    float2 v = make_float2((r == c) ? 1.f : 0.f, 0.f);
    g_W[idx] = v;
    g_Wold[idx] = v;
  }
}

// ---------- transpose X(M,J,I,2) -> g_Xc(I,J,M); both m fused, float4 writes ----------
__global__ __launch_bounds__(256) void k_transpose(const float* __restrict__ X) {
  __shared__ float2 s0[32][65];   // [jj][ii], m=0
  __shared__ float2 s1[32][65];   // m=1
  int i0 = blockIdx.x*64, j0 = blockIdx.y*32;
  int lane = threadIdx.x & 63, row = threadIdx.x >> 6;
  const float2* X2 = (const float2*)X;   // (m*J + j)*I + i
  int gi = i0 + lane;
  if (gi < I_) {
    for (int jj = row; jj < 32; jj += 4) {
      s0[jj][lane] = X2[(size_t)(0*J_ + j0 + jj)*I_ + gi];
      s1[jj][lane] = X2[(size_t)(1*J_ + j0 + jj)*I_ + gi];
    }
  }
  __syncthreads();
  int jj = threadIdx.x & 31, ii0 = threadIdx.x >> 5;   // 32 lanes = 32 consecutive j (512B line)
  for (int u = 0; u < 8; u++) {
    int ii = ii0*8 + u;
    int i = i0 + ii;
    if (i < I_) {
      float2 a = s0[jj][ii], b = s1[jj][ii];
      g_Xc[(size_t)i*J_ + j0 + jj] = make_float4(a.x, a.y, b.x, b.y);
    }
  }
}

// ---------- fused per-i kernel: [D-accum + mid-block solve] (doD) + T-update ----------
// The 8 Xc row registers are loaded ONCE (wave-sliced mapping) and reused by BOTH
// phases across the barrier — named float4s, so no LDS promotion (round-8 lesson).
__global__ __launch_bounds__(256, 2) void k_tv(int doD) {
  int i = blockIdx.x, t = threadIdx.x;
  int wv = t >> 6, lane = t & 63;
  __shared__ float redD[4][12];
  __shared__ float2 sW[4];
  __shared__ float redT[4][32];

  const float4* T4 = (const float4*)g_Tt;
  float4 tt0 = T4[i*4+0], tt1 = T4[i*4+1];   // n=0: k0-3, k4-7
  float4 tt2 = T4[i*4+2], tt3 = T4[i*4+3];   // n=1

  // ---- single Xc row load, wave-sliced mapping; reused by phase 1 AND phase 2 ----
  size_t xb = (size_t)i*J_ + wv*512 + lane;
  float4 xv0 = g_Xc[xb+0*64], xv1 = g_Xc[xb+1*64], xv2 = g_Xc[xb+2*64], xv3 = g_Xc[xb+3*64];
  float4 xv4 = g_Xc[xb+4*64], xv5 = g_Xc[xb+5*64], xv6 = g_Xc[xb+6*64], xv7 = g_Xc[xb+7*64];

  if (doD) {
    // ---- phase 1: D moments over this wave's 512-j slice ----
    float s0=0.f,s1=0.f,s2=0.f,s3=0.f,s4=0.f,s5=0.f,s6=0.f,s7=0.f,s8=0.f,s9=0.f,s10=0.f,s11=0.f;
#define DB(U) { int j = wv*512 + U*64 + lane; \
    const float4* Vp = g_Vt4 + (size_t)j*4; \
    float4 vt0=Vp[0], vt1=Vp[1], vt2=Vp[2], vt3=Vp[3]; \
    float rn0 = dot44(tt0,vt0)+dot44(tt1,vt1); \
    float rn1 = dot44(tt2,vt2)+dot44(tt3,vt3); \
    float a0=xv##U.x, b0=xv##U.y, a1=xv##U.z, b1=xv##U.w; \
    float e00r=a0*a0-b0*b0, e00i=2.f*a0*b0; \
    float e01r=a0*a1-b0*b1, e01i=a0*b1+a1*b0; \
    float e11r=a1*a1-b1*b1, e11i=2.f*a1*b1; \
    float inv0=frcp(rn0), inv1=frcp(rn1); \
    s0=fmaf(e00r,inv0,s0);  s1=fmaf(e00i,inv0,s1); \
    s2=fmaf(e01r,inv0,s2);  s3=fmaf(e01i,inv0,s3); \
    s4=fmaf(e11r,inv0,s4);  s5=fmaf(e11i,inv0,s5); \
    s6=fmaf(e00r,inv1,s6);  s7=fmaf(e00i,inv1,s7); \
    s8=fmaf(e01r,inv1,s8);  s9=fmaf(e01i,inv1,s9); \
    s10=fmaf(e11r,inv1,s10); s11=fmaf(e11i,inv1,s11); }
    DB(0) DB(1) DB(2) DB(3) DB(4) DB(5) DB(6) DB(7)
#undef DB
    RW(s0) RW(s1) RW(s2) RW(s3) RW(s4) RW(s5) RW(s6) RW(s7) RW(s8) RW(s9) RW(s10) RW(s11)
    if (lane == 0) {
      redD[wv][0]=s0;  redD[wv][1]=s1;  redD[wv][2]=s2;  redD[wv][3]=s3;
      redD[wv][4]=s4;  redD[wv][5]=s5;  redD[wv][6]=s6;  redD[wv][7]=s7;
      redD[wv][8]=s8;  redD[wv][9]=s9;  redD[wv][10]=s10; redD[wv][11]=s11;
    }
    __syncthreads();
    if (t == 0) {
      double s_[12];
#pragma unroll
      for (int q = 0; q < 12; q++)
        s_[q] = (double)redD[0][q] + (double)redD[1][q] + (double)redD[2][q] + (double)redD[3][q];
      float2 w[4];
      solve12(i, s_, w);
      sW[0] = w[0]; sW[1] = w[1]; sW[2] = w[2]; sW[3] = w[3];
    }
  } else {
    if (t == 0) {
      sW[0] = g_Wold[(size_t)i*4+0]; sW[1] = g_Wold[(size_t)i*4+1];
      sW[2] = g_Wold[(size_t)i*4+2]; sW[3] = g_Wold[(size_t)i*4+3];
    }
  }
  __syncthreads();
  float2 w00 = sW[0], w01 = sW[1], w10 = sW[2], w11 = sW[3];

  // ---- phase 2: T update — SAME xv registers, same wave-sliced j mapping ----
  float4 z = make_float4(0.f,0.f,0.f,0.f);
  float4 aN0a=z, aN0b=z, aD0a=z, aD0b=z, aN1a=z, aN1b=z, aD1a=z, aD1b=z;
#define TB(U) { int j = wv*512 + U*64 + lane; \
  const float4* Vp = g_Vt4 + (size_t)j*4; \
  float4 vt0=Vp[0], vt1=Vp[1], vt2=Vp[2], vt3=Vp[3]; \
  float rn0 = dot44(tt0,vt0)+dot44(tt1,vt1); \
  float rn1 = dot44(tt2,vt2)+dot44(tt3,vt3); \
  float2 x0=make_float2(xv##U.x,xv##U.y), x1=make_float2(xv##U.z,xv##U.w); \
  float2 y0=cyn(w00,w01,x0,x1), y1=cyn(w10,w11,x0,x1); \
  float p0=(y0.x*y0.x+y0.y*y0.y)*frcp(rn0*rn0+EPSF); \
  float p1=(y1.x*y1.x+y1.y*y1.y)*frcp(rn1*rn1+EPSF); \
  float rd0=frcp(rn0), rd1=frcp(rn1); \
  aN0a=f4fma(p0,vt0,aN0a); aN0b=f4fma(p0,vt1,aN0b); \
  aD0a=f4fma(rd0,vt0,aD0a); aD0b=f4fma(rd0,vt1,aD0b); \
  aN1a=f4fma(p1,vt2,aN1a); aN1b=f4fma(p1,vt3,aN1b); \
  aD1a=f4fma(rd1,vt2,aD1a); aD1b=f4fma(rd1,vt3,aD1b); }
  TB(0) TB(1) TB(2) TB(3) TB(4) TB(5) TB(6) TB(7)
#undef TB
  aN0a = wred4(aN0a); aN0b = wred4(aN0b); aD0a = wred4(aD0a); aD0b = wred4(aD0b);
  aN1a = wred4(aN1a); aN1b = wred4(aN1b); aD1a = wred4(aD1a); aD1b = wred4(aD1b);
  if (lane == 0) {
    redT[wv][0]=aN0a.x;  redT[wv][1]=aN0a.y;  redT[wv][2]=aN0a.z;  redT[wv][3]=aN0a.w;
    redT[wv][4]=aN0b.x;  redT[wv][5]=aN0b.y;  redT[wv][6]=aN0b.z;  redT[wv][7]=aN0b.w;
    redT[wv][8]=aD0a.x;  redT[wv][9]=aD0a.y;  redT[wv][10]=aD0a.z; redT[wv][11]=aD0a.w;
    redT[wv][12]=aD0b.x; redT[wv][13]=aD0b.y; redT[wv][14]=aD0b.z; redT[wv][15]=aD0b.w;
    redT[wv][16]=aN1a.x; redT[wv][17]=aN1a.y; redT[wv][18]=aN1a.z; redT[wv][19]=aN1a.w;
    redT[wv][20]=aN1b.x; redT[wv][21]=aN1b.y; redT[wv][22]=aN1b.z; redT[wv][23]=aN1b.w;
    redT[wv][24]=aD1a.x; redT[wv][25]=aD1a.y; redT[wv][26]=aD1a.z; redT[wv][27]=aD1a.w;
    redT[wv][28]=aD1b.x; redT[wv][29]=aD1b.y; redT[wv][30]=aD1b.z; redT[wv][31]=aD1b.w;
  }
  __syncthreads();
  if (t < 8) {
    int k = t;
    float n0 = redT[0][k]    + redT[1][k]    + redT[2][k]    + redT[3][k];
    float d0 = redT[0][8+k]  + redT[1][8+k]  + redT[2][8+k]  + redT[3][8+k];
    float n1 = redT[0][16+k] + redT[1][16+k] + redT[2][16+k] + redT[3][16+k];
    float d1 = redT[0][24+k] + redT[1][24+k] + redT[2][24+k] + redT[3][24+k];
    float tvx = g_Tt[i*16 + k], tvy = g_Tt[i*16 + 8 + k];
    g_Toldt[i*16 + k]     = tvx;
    g_Toldt[i*16 + 8 + k] = tvy;
    g_Tt[i*16 + k]     = tvx * sqrtf(n0/d0);
    g_Tt[i*16 + 8 + k] = tvy * sqrtf(n1/d1);
  }
}

// ---------- V partial accumulation; float4 T/Told from LDS; named accumulators ----------
__global__ __launch_bounds__(256, 2) void k_vupd2() {
  int t  = threadIdx.x;
  int j  = blockIdx.x*256 + t;
  int c  = blockIdx.y;
  int i0 = c*CHUNK;
  int ni = I_ - i0; if (ni > CHUNK) ni = CHUNK;

  __shared__ float2 sWold[CHUNK*4];
  __shared__ float4 sTold[CHUNK*4];
  __shared__ float4 sT[CHUNK*4];
  const float4* To4 = (const float4*)g_Toldt;
  const float4* Tn4 = (const float4*)g_Tt;
  if (t < CHUNK*4) {
    int g = i0*4 + t; if (g < I_*4) sWold[t] = g_Wold[g];
  } else if (t < CHUNK*8) {
    int u = t - CHUNK*4; int g = i0*4 + u; if (g < I_*4) sTold[u] = To4[g];
  } else if (t < CHUNK*12) {
    int u = t - CHUNK*8; int g = i0*4 + u; if (g < I_*4) sT[u] = Tn4[g];
  }
  __syncthreads();

  const float4* Vp = g_Vt4 + (size_t)j*4;
  float4 vt0 = Vp[0], vt1 = Vp[1], vt2 = Vp[2], vt3 = Vp[3];
  float4 z = make_float4(0.f,0.f,0.f,0.f);
  float4 aN0a=z, aN0b=z, aD0a=z, aD0b=z, aN1a=z, aN1b=z, aD1a=z, aD1b=z;

  auto body = [&](int ii, float4 xv) {
    float2 x0 = make_float2(xv.x, xv.y), x1 = make_float2(xv.z, xv.w);
    float2 w00 = sWold[ii*4+0], w01 = sWold[ii*4+1], w10 = sWold[ii*4+2], w11 = sWold[ii*4+3];
    float4 to0 = sTold[ii*4+0], to1 = sTold[ii*4+1], to2 = sTold[ii*4+2], to3 = sTold[ii*4+3];
    float rn0 = dot44(to0,vt0)+dot44(to1,vt1);
    float rn1 = dot44(to2,vt2)+dot44(to3,vt3);
    float2 y0 = cyn(w00,w01,x0,x1), y1 = cyn(w10,w11,x0,x1);
    float p0 = (y0.x*y0.x+y0.y*y0.y)*frcp(rn0*rn0+EPSF);
    float p1 = (y1.x*y1.x+y1.y*y1.y)*frcp(rn1*rn1+EPSF);
    float rd0 = frcp(rn0), rd1 = frcp(rn1);
    float4 st0 = sT[ii*4+0], st1 = sT[ii*4+1], st2 = sT[ii*4+2], st3 = sT[ii*4+3];
    aN0a = f4fma(p0,  st0, aN0a); aN0b = f4fma(p0,  st1, aN0b);
    aD0a = f4fma(rd0, st0, aD0a); aD0b = f4fma(rd0, st1, aD0b);
    aN1a = f4fma(p1,  st2, aN1a); aN1b = f4fma(p1,  st3, aN1b);
    aD1a = f4fma(rd1, st2, aD1a); aD1b = f4fma(rd1, st3, aD1b);
  };

  int ii = 0;
  for (; ii + 8 <= ni; ii += 8) {
    float4 xA = g_Xc[(size_t)(i0+ii+0)*J_ + j];
    float4 xB = g_Xc[(size_t)(i0+ii+1)*J_ + j];
    float4 xC = g_Xc[(size_t)(i0+ii+2)*J_ + j];
    float4 xD = g_Xc[(size_t)(i0+ii+3)*J_ + j];
    float4 xE = g_Xc[(size_t)(i0+ii+4)*J_ + j];
    float4 xF = g_Xc[(size_t)(i0+ii+5)*J_ + j];
    float4 xG = g_Xc[(size_t)(i0+ii+6)*J_ + j];
    float4 xH = g_Xc[(size_t)(i0+ii+7)*J_ + j];
    body(ii+0,xA); body(ii+1,xB); body(ii+2,xC); body(ii+3,xD);
    body(ii+4,xE); body(ii+5,xF); body(ii+6,xG); body(ii+7,xH);
  }
  for (; ii < ni; ii++) body(ii, g_Xc[(size_t)(i0+ii)*J_ + j]);

  size_t b2 = (size_t)c*2*J_;
  g_pnA[b2 + j] = aN0a;  g_pnA[b2 + J_ + j] = aN0b;
  g_pnB[b2 + j] = aN1a;  g_pnB[b2 + J_ + j] = aN1b;
  g_pdA[b2 + j] = aD0a;  g_pdA[b2 + J_ + j] = aD0b;
  g_pdB[b2 + j] = aD1a;  g_pdB[b2 + J_ + j] = aD1b;
}

// ---------- chunk-reduce partials + apply Vt *= sqrt(num/den); float4 wide ----------
__global__ __launch_bounds__(256) void k_vapply2() {
  int t = threadIdx.x;
  int g = blockIdx.x*16 + (t & 15);         // (kg,j) group: kg = g>>11, j = g&2047
  int slice = t >> 4;                       // 16 c-slices of 9 (16*9=144 >= 129)
  int kg = g >> 11, j = g & (J_-1);
  int c0 = slice*9, c1 = c0 + 9; if (c1 > NCHUNK) c1 = NCHUNK;
  float4 z = make_float4(0.f,0.f,0.f,0.f);
  float4 sNa=z, sNb=z, sDa=z, sDb=z;
  for (int c = c0; c < c1; c++) {
    size_t o = (size_t)c*2*J_ + (size_t)kg*J_ + j;
    sNa = f4add(sNa, g_pnA[o]); sNb = f4add(sNb, g_pnB[o]);
    sDa = f4add(sDa, g_pdA[o]); sDb = f4add(sDb, g_pdB[o]);
  }
  __shared__ float4 rNa[16][16], rNb[16][16], rDa[16][16], rDb[16][16];
  rNa[slice][t & 15] = sNa; rNb[slice][t & 15] = sNb;
  rDa[slice][t & 15] = sDa; rDb[slice][t & 15] = sDb;
  __syncthreads();
  if (t < 16) {
    float4 na = rNa[0][t], nb = rNb[0][t], da = rDa[0][t], db = rDb[0][t];
#pragma unroll
    for (int s = 1; s < 16; s++) {
      na = f4add(na, rNa[s][t]); nb = f4add(nb, rNb[s][t]);
      da = f4add(da, rDa[s][t]); db = f4add(db, rDb[s][t]);
    }
    int gg = blockIdx.x*16 + t;
    int kg2 = gg >> 11, j2 = gg & (J_-1);
    float4 v0 = g_Vt4[(size_t)j2*4 + kg2];       // n=0, k-group kg2
    float4 v1 = g_Vt4[(size_t)j2*4 + 2 + kg2];   // n=1
    v0.x *= sqrtf(na.x/da.x); v0.y *= sqrtf(na.y/da.y); v0.z *= sqrtf(na.z/da.z); v0.w *= sqrtf(na.w/da.w);
    v1.x *= sqrtf(nb.x/db.x); v1.y *= sqrtf(nb.y/db.y); v1.z *= sqrtf(nb.z/db.z); v1.w *= sqrtf(nb.w/db.w);
    g_Vt4[(size_t)j2*4 + kg2] = v0;
    g_Vt4[(size_t)j2*4 + 2 + kg2] = v1;
  }
}

// ---------- final: fused D-accum + solve + Y = W · Xc output (registers reused) ----------
__global__ __launch_bounds__(256, 2) void k_yout(float* __restrict__ out, int cplx) {
  int i = blockIdx.x, t = threadIdx.x;
  int wv = t >> 6, lane = t & 63;
  __shared__ float redD[4][12];
  __shared__ float2 sW[4];

  const float4* T4 = (const float4*)g_Tt;
  float4 tt0 = T4[i*4+0], tt1 = T4[i*4+1], tt2 = T4[i*4+2], tt3 = T4[i*4+3];

  // single Xc row load, wave-sliced mapping; reused by the Y phase
  size_t xb = (size_t)i*J_ + wv*512 + lane;
  float4 xv0 = g_Xc[xb+0*64], xv1 = g_Xc[xb+1*64], xv2 = g_Xc[xb+2*64], xv3 = g_Xc[xb+3*64];
  float4 xv4 = g_Xc[xb+4*64], xv5 = g_Xc[xb+5*64], xv6 = g_Xc[xb+6*64], xv7 = g_Xc[xb+7*64];

  {
    float s0=0.f,s1=0.f,s2=0.f,s3=0.f,s4=0.f,s5=0.f,s6=0.f,s7=0.f,s8=0.f,s9=0.f,s10=0.f,s11=0.f;
#define DB(U) { int j = wv*512 + U*64 + lane; \
    const float4* Vp = g_Vt4 + (size_t)j*4; \
    float4 vt0=Vp[0], vt1=Vp[1], vt2=Vp[2], vt3=Vp[3]; \
    float rn0 = dot44(tt0,vt0)+dot44(tt1,vt1); \
    float rn1 = dot44(tt2,vt2)+dot44(tt3,vt3); \
    float a0=xv##U.x, b0=xv##U.y, a1=xv##U.z, b1=xv##U.w; \
    float e00r=a0*a0-b0*b0, e00i=2.f*a0*b0; \
    float e01r=a0*a1-b0*b1, e01i=a0*b1+a1*b0; \
    float e11r=a1*a1-b1*b1, e11i=2.f*a1*b1; \
    float inv0=frcp(rn0), inv1=frcp(rn1); \
    s0=fmaf(e00r,inv0,s0);  s1=fmaf(e00i,inv0,s1); \
    s2=fmaf(e01r,inv0,s2);  s3=fmaf(e01i,inv0,s3); \
    s4=fmaf(e11r,inv0,s4);  s5=fmaf(e11i,inv0,s5); \
    s6=fmaf(e00r,inv1,s6);  s7=fmaf(e00i,inv1,s7); \
    s8=fmaf(e01r,inv1,s8);  s9=fmaf(e01i,inv1,s9); \
    s10=fmaf(e11r,inv1,s10); s11=fmaf(e11i,inv1,s11); }
    DB(0) DB(1) DB(2) DB(3) DB(4) DB(5) DB(6) DB(7)
#undef DB
    RW(s0) RW(s1) RW(s2) RW(s3) RW(s4) RW(s5) RW(s6) RW(s7) RW(s8) RW(s9) RW(s10) RW(s11)
    if (lane == 0) {
      redD[wv][0]=s0;  redD[wv][1]=s1;  redD[wv][2]=s2;  redD[wv][3]=s3;
      redD[wv][4]=s4;  redD[wv][5]=s5;  redD[wv][6]=s6;  redD[wv][7]=s7;
      redD[wv][8]=s8;  redD[wv][9]=s9;  redD[wv][10]=s10; redD[wv][11]=s11;
    }
  }
  __syncthreads();
  if (t == 0) {
    double s_[12];
#pragma unroll
    for (int q = 0; q < 12; q++)
      s_[q] = (double)redD[0][q] + (double)redD[1][q] + (double)redD[2][q] + (double)redD[3][q];
    float2 w[4];
    solve12(i, s_, w);
    sW[0] = w[0]; sW[1] = w[1]; sW[2] = w[2]; sW[3] = w[3];
  }
  __syncthreads();
  float2 w00 = sW[0], w01 = sW[1], w10 = sW[2], w11 = sW[3];
  float2* out2 = (float2*)out;
#define YB(U) { int j = wv*512 + U*64 + lane; \
  float2 x0 = make_float2(xv##U.x, xv##U.y); \
  float2 x1 = make_float2(xv##U.z, xv##U.w); \
  float2 y0 = cyn(w00, w01, x0, x1); \
  float2 y1 = cyn(w10, w11, x0, x1); \
  if (cplx) { \
    out2[((size_t)i*N_ + 0)*J_ + j] = y0; \
    out2[((size_t)i*N_ + 1)*J_ + j] = y1; \
  } else { \
    out[((size_t)i*N_ + 0)*J_ + j] = y0.x; \
    out[((size_t)i*N_ + 1)*J_ + j] = y1.x; \
  } }
  YB(0) YB(1) YB(2) YB(3) YB(4) YB(5) YB(6) YB(7)
#undef YB
}

extern "C" void kernel_launch(void* const* d_in, const int* in_sizes, int n_in,
                              void* d_out, int out_size, void* d_ws, size_t ws_size,
                              hipStream_t stream) {
  const float* X  = (const float*)d_in[0];
  const float* T0 = (const float*)d_in[1];
  const float* V0 = (const float*)d_in[2];
  (void)d_ws; (void)ws_size;

  // grid covers I_*K_ = 16392 (largest init domain) — 65 blocks
  k_setup<<<(I_*K_ + 255)/256, 256, 0, stream>>>(T0, V0);
  k_transpose<<<dim3((I_ + 63)/64, J_/32), 256, 0, stream>>>(X);

  int cplx = (out_size >= 2*I_*N_*J_) ? 1 : 0;
  for (int it = 0; it < NITER; it++) {
    // it>0: k_tv solves W(it) in-block from its own D phase (prev iter's T,V), then T-update
    k_tv<<<I_, 256, 0, stream>>>(it > 0);
    k_vupd2<<<dim3(J_/256, NCHUNK), 256, 0, stream>>>();
    k_vapply2<<<2*J_/16, 256, 0, stream>>>();
  }
  k_yout<<<I_, 256, 0, stream>>>((float*)d_out, cplx);   // fused final D + solve + Y
}